// Round 4
// baseline (471.457 us; speedup 1.0000x reference)
//
#include <hip/hip_runtime.h>
#include <math.h>

#define N_NODES 50000
#define N_EDGES 800000
#define FD 128

// ---- workspace layout (bytes) ----
#define WS_DEG    0u          // int[N]
#define WS_CURSOR 200000u     // int[N]
#define WS_OFF    400000u     // int[N+1]
#define WS_AUX    600320u     // int[256]
#define WS_ESRC   601600u     // int[E] -> ends 3801600
#define WS_WT     3801600u    // bf16[8*128*128] -> ends 4063744
#define WS_XB     4063744u    // bf16[N*128] -> 16863744
#define WS_HB     16863744u   // bf16[N*128] -> 29663744
#define WS_Q      29663744u   // bf16[N*128]
#define WS_K      42463744u
#define WS_V      55263744u
#define WS_S      68063744u   // ends 80863744 (~81 MB)

typedef unsigned short ushort_t;
typedef unsigned int uint_t;
typedef __attribute__((ext_vector_type(8))) short short8;
typedef __attribute__((ext_vector_type(4))) float floatx4;

__device__ __forceinline__ ushort_t f2bf(float f) {
    uint_t u = __float_as_uint(f);
    return (ushort_t)((u + 0x7FFFu + ((u >> 16) & 1u)) >> 16);   // RNE
}
__device__ __forceinline__ float bf2f_lo(uint_t u) { return __uint_as_float(u << 16); }
__device__ __forceinline__ float bf2f_hi(uint_t u) { return __uint_as_float(u & 0xFFFF0000u); }

// ---------------- fp32 -> bf16 bulk convert ----------------
__global__ void cvt_k(const float* __restrict__ X, ushort_t* __restrict__ O, int n4) {
    int i = blockIdx.x * 256 + threadIdx.x;
    if (i < n4) {
        float4 vv = ((const float4*)X)[i];
        ushort_t p[4] = {f2bf(vv.x), f2bf(vv.y), f2bf(vv.z), f2bf(vv.w)};
        ((ushort4*)O)[i] = *(ushort4*)p;
    }
}

// ---------------- W -> W^T bf16 (8 matrices, one block each) ----------------
__global__ __launch_bounds__(256) void wt_k(
    const float* __restrict__ W0, const float* __restrict__ W1,
    const float* __restrict__ W2, const float* __restrict__ W3,
    const float* __restrict__ W4, const float* __restrict__ W5,
    const float* __restrict__ W6, const float* __restrict__ W7,
    ushort_t* __restrict__ Wt)
{
    const int m = blockIdx.x;
    const float* W = (m==0)?W0:(m==1)?W1:(m==2)?W2:(m==3)?W3:(m==4)?W4:(m==5)?W5:(m==6)?W6:W7;
    ushort_t* O = Wt + m * (FD * FD);
    #pragma unroll
    for (int it = 0; it < 16; ++it) {
        int i = threadIdx.x + it * 256;       // 0..4095
        int n = i & 127, k4 = (i >> 7) << 2;  // k4 in {0,4,...,124}
        ushort_t p[4];
        p[0] = f2bf(W[(k4 + 0) * FD + n]);
        p[1] = f2bf(W[(k4 + 1) * FD + n]);
        p[2] = f2bf(W[(k4 + 2) * FD + n]);
        p[3] = f2bf(W[(k4 + 3) * FD + n]);
        *(ushort4*)(O + n * FD + k4) = *(ushort4*)p;   // Wt[n][k]
    }
}

// ---------------- CSR build ----------------
__global__ void hist_k(const int* __restrict__ ei, int* __restrict__ deg, int E) {
    int e = blockIdx.x * blockDim.x + threadIdx.x;
    if (e < E) atomicAdd(&deg[ei[E + e]], 1);   // ei[E+e] = dst
}

__global__ __launch_bounds__(256) void scan1_k(const int* __restrict__ deg,
                                               int* __restrict__ off,
                                               int* __restrict__ aux, int n) {
    __shared__ int sbuf[256];
    int tid = threadIdx.x;
    int idx = blockIdx.x * 256 + tid;
    int val = (idx < n) ? deg[idx] : 0;
    sbuf[tid] = val;
    __syncthreads();
    #pragma unroll
    for (int d = 1; d < 256; d <<= 1) {
        int t = (tid >= d) ? sbuf[tid - d] : 0;
        __syncthreads();
        sbuf[tid] += t;
        __syncthreads();
    }
    int incl = sbuf[tid];
    if (idx < n) off[idx] = incl - val;
    if (tid == 255) aux[blockIdx.x] = incl;
}

__global__ __launch_bounds__(256) void scan2_k(int* __restrict__ aux,
                                               int* __restrict__ off,
                                               int nblocks, int n, int total) {
    __shared__ int sbuf[256];
    int tid = threadIdx.x;
    int val = (tid < nblocks) ? aux[tid] : 0;
    sbuf[tid] = val;
    __syncthreads();
    #pragma unroll
    for (int d = 1; d < 256; d <<= 1) {
        int t = (tid >= d) ? sbuf[tid - d] : 0;
        __syncthreads();
        sbuf[tid] += t;
        __syncthreads();
    }
    if (tid < nblocks) aux[tid] = sbuf[tid] - val;
    if (tid == 0) off[n] = total;
}

__global__ __launch_bounds__(256) void scan3_k(int* __restrict__ off,
                                               const int* __restrict__ aux, int n) {
    int idx = blockIdx.x * 256 + threadIdx.x;
    if (idx < n) off[idx] += aux[blockIdx.x];
}

__global__ void scatter_k(const int* __restrict__ ei, const int* __restrict__ off,
                          int* __restrict__ cursor, int* __restrict__ esrc, int E) {
    int e = blockIdx.x * blockDim.x + threadIdx.x;
    if (e < E) {
        int d = ei[E + e];
        int pos = off[d] + atomicAdd(&cursor[d], 1);
        esrc[pos] = ei[e];                            // ei[e] = src
    }
}

// ---------------- MFMA bf16 GEMM: O_m = X @ W_m + b_m, m=0..3 ----------------
// grid ceil(N/64) blocks, 256 thr (4 waves). Block stages one 64x128 bf16 X tile
// in LDS once; loops 4 matrices; B fragments loaded straight from global W^T
// (256 KB, L2-resident). Wave owns 16 rows; 8 n-tiles x 4 k-steps.
__global__ __launch_bounds__(256) void gemm_mfma_k(
    const ushort_t* __restrict__ Xb, const ushort_t* __restrict__ Wt,
    const float* __restrict__ b0, const float* __restrict__ b1,
    const float* __restrict__ b2, const float* __restrict__ b3,
    ushort_t* __restrict__ O0, ushort_t* __restrict__ O1,
    ushort_t* __restrict__ O2, ushort_t* __restrict__ O3, int N)
{
    __shared__ ushort_t As[64][136];   // 17408 B
    const int tid = threadIdx.x;
    const int row0 = blockIdx.x * 64;

    #pragma unroll
    for (int it = 0; it < 4; ++it) {
        int i = tid + it * 256;          // 1024 x 16B chunks
        int r = i >> 4, c8 = (i & 15) * 8;
        int gr = row0 + r;
        uint4 val = make_uint4(0, 0, 0, 0);
        if (gr < N) val = *(const uint4*)(Xb + (size_t)gr * FD + c8);
        *(uint4*)(&As[r][c8]) = val;
    }
    __syncthreads();

    const int wid = tid >> 6, lane = tid & 63;
    const int quad = lane >> 4, col_l = lane & 15;
    const int ar = wid * 16 + col_l;

    #pragma unroll 1
    for (int m = 0; m < 4; ++m) {
        const ushort_t* Wm = Wt + m * (FD * FD);
        const float* B = (m == 0) ? b0 : (m == 1) ? b1 : (m == 2) ? b2 : b3;
        ushort_t* O = (m == 0) ? O0 : (m == 1) ? O1 : (m == 2) ? O2 : O3;

        floatx4 acc[8];
        #pragma unroll
        for (int nt = 0; nt < 8; ++nt) acc[nt] = (floatx4){0.f, 0.f, 0.f, 0.f};

        #pragma unroll
        for (int ks = 0; ks < 4; ++ks) {
            const int kb = ks * 32 + quad * 8;
            short8 a = *(const short8*)(&As[ar][kb]);
            #pragma unroll
            for (int nt = 0; nt < 8; ++nt) {
                short8 b = *(const short8*)(Wm + (size_t)(nt * 16 + col_l) * FD + kb);
                acc[nt] = __builtin_amdgcn_mfma_f32_16x16x32_bf16(a, b, acc[nt], 0, 0, 0);
            }
        }

        const int grow = row0 + wid * 16 + quad * 4;
        #pragma unroll
        for (int nt = 0; nt < 8; ++nt) {
            const int col = nt * 16 + col_l;
            const float bv = B[col];
            #pragma unroll
            for (int r = 0; r < 4; ++r) {
                int gr = grow + r;
                if (gr < N) O[(size_t)gr * FD + col] = f2bf(acc[nt][r] + bv);
            }
        }
    }
}

// ---------------- per-dst attention (16-lane edge groups, no-max softmax) ----------------
__global__ __launch_bounds__(256) void attn_k(
    const ushort_t* __restrict__ q, const ushort_t* __restrict__ k,
    const ushort_t* __restrict__ v, const ushort_t* __restrict__ sp,
    const int* __restrict__ off, const int* __restrict__ esrc,
    ushort_t* __restrict__ out_bf, float* __restrict__ out_f,
    int relu, int bf16out, int N)
{
    const int wid = threadIdx.x >> 6;
    const int lane = threadIdx.x & 63;
    const int g = lane >> 4;         // edge group 0..3
    const int j = lane & 15;         // lane within group
    const int dst = blockIdx.x * 4 + wid;
    if (dst >= N) return;

    const int beg = off[dst];
    const int end = off[dst + 1];
    const int f0 = j * 8;

    const uint4 qu = *(const uint4*)(q + ((size_t)dst << 7) + f0);
    float qf[8];
    qf[0] = bf2f_lo(qu.x); qf[1] = bf2f_hi(qu.x);
    qf[2] = bf2f_lo(qu.y); qf[3] = bf2f_hi(qu.y);
    qf[4] = bf2f_lo(qu.z); qf[5] = bf2f_hi(qu.z);
    qf[6] = bf2f_lo(qu.w); qf[7] = bf2f_hi(qu.w);

    const float scale = 0.08838834764831845f;   // 1/sqrt(128)
    float l = 0.f;
    float acc[8];
    #pragma unroll
    for (int i = 0; i < 8; ++i) acc[i] = 0.f;

    const int last = end - 1;
    for (int base = beg; base < end; base += 8) {
        const int e0 = base + g;
        const int e1 = base + 4 + g;
        const int i0 = (e0 <= last) ? e0 : last;
        const int i1 = (e1 <= last) ? e1 : last;
        const int s0 = esrc[i0];
        const int s1 = esrc[i1];

        const uint4 k0 = *(const uint4*)(k + ((size_t)s0 << 7) + f0);
        const uint4 k1 = *(const uint4*)(k + ((size_t)s1 << 7) + f0);

        float p0 = qf[0] * bf2f_lo(k0.x);
        p0 = fmaf(qf[1], bf2f_hi(k0.x), p0);
        p0 = fmaf(qf[2], bf2f_lo(k0.y), p0);
        p0 = fmaf(qf[3], bf2f_hi(k0.y), p0);
        p0 = fmaf(qf[4], bf2f_lo(k0.z), p0);
        p0 = fmaf(qf[5], bf2f_hi(k0.z), p0);
        p0 = fmaf(qf[6], bf2f_lo(k0.w), p0);
        p0 = fmaf(qf[7], bf2f_hi(k0.w), p0);

        float p1 = qf[0] * bf2f_lo(k1.x);
        p1 = fmaf(qf[1], bf2f_hi(k1.x), p1);
        p1 = fmaf(qf[2], bf2f_lo(k1.y), p1);
        p1 = fmaf(qf[3], bf2f_hi(k1.y), p1);
        p1 = fmaf(qf[4], bf2f_lo(k1.z), p1);
        p1 = fmaf(qf[5], bf2f_hi(k1.z), p1);
        p1 = fmaf(qf[6], bf2f_lo(k1.w), p1);
        p1 = fmaf(qf[7], bf2f_hi(k1.w), p1);

        #pragma unroll
        for (int i = 1; i <= 8; i <<= 1) {
            p0 += __shfl_xor(p0, i, 64);
            p1 += __shfl_xor(p1, i, 64);
        }

        float w0 = __expf(p0 * scale);
        float w1 = __expf(p1 * scale);
        if (e0 > last) w0 = 0.f;
        if (e1 > last) w1 = 0.f;

        const uint4 v0 = *(const uint4*)(v + ((size_t)s0 << 7) + f0);
        const uint4 v1 = *(const uint4*)(v + ((size_t)s1 << 7) + f0);

        l += w0 + w1;
        acc[0] = fmaf(w0, bf2f_lo(v0.x), fmaf(w1, bf2f_lo(v1.x), acc[0]));
        acc[1] = fmaf(w0, bf2f_hi(v0.x), fmaf(w1, bf2f_hi(v1.x), acc[1]));
        acc[2] = fmaf(w0, bf2f_lo(v0.y), fmaf(w1, bf2f_lo(v1.y), acc[2]));
        acc[3] = fmaf(w0, bf2f_hi(v0.y), fmaf(w1, bf2f_hi(v1.y), acc[3]));
        acc[4] = fmaf(w0, bf2f_lo(v0.z), fmaf(w1, bf2f_lo(v1.z), acc[4]));
        acc[5] = fmaf(w0, bf2f_hi(v0.z), fmaf(w1, bf2f_hi(v1.z), acc[5]));
        acc[6] = fmaf(w0, bf2f_lo(v0.w), fmaf(w1, bf2f_lo(v1.w), acc[6]));
        acc[7] = fmaf(w0, bf2f_hi(v0.w), fmaf(w1, bf2f_hi(v1.w), acc[7]));
    }

    #pragma unroll
    for (int i = 0; i < 8; ++i) {
        acc[i] += __shfl_xor(acc[i], 16, 64);
        acc[i] += __shfl_xor(acc[i], 32, 64);
    }
    l += __shfl_xor(l, 16, 64);
    l += __shfl_xor(l, 32, 64);

    const float inv = 1.0f / ((l == 0.f) ? 1.f : l);
    const int fo = f0 + g * 2;                          // lane stores 2 feats
    const uint_t su = *(const uint_t*)(sp + ((size_t)dst << 7) + fo);
    float ox = acc[g * 2]     * inv + bf2f_lo(su);
    float oy = acc[g * 2 + 1] * inv + bf2f_hi(su);
    if (relu) { ox = fmaxf(ox, 0.f); oy = fmaxf(oy, 0.f); }
    if (bf16out) {
        ushort_t p2[2] = {f2bf(ox), f2bf(oy)};
        *(uint_t*)(out_bf + ((size_t)dst << 7) + fo) = *(uint_t*)p2;
    } else {
        *(float2*)(out_f + ((size_t)dst << 7) + fo) = make_float2(ox, oy);
    }
}

// ---------------- launch ----------------
extern "C" void kernel_launch(void* const* d_in, const int* in_sizes, int n_in,
                              void* d_out, int out_size, void* d_ws, size_t ws_size,
                              hipStream_t stream) {
    const float* x  = (const float*)d_in[0];
    const int*   ei = (const int*)d_in[1];   // [2,E]: row0=src, row1=dst
    const float* Wq1 = (const float*)d_in[2],  *bq1 = (const float*)d_in[3];
    const float* Wk1 = (const float*)d_in[4],  *bk1 = (const float*)d_in[5];
    const float* Wv1 = (const float*)d_in[6],  *bv1 = (const float*)d_in[7];
    const float* Ws1 = (const float*)d_in[8],  *bs1 = (const float*)d_in[9];
    const float* Wq2 = (const float*)d_in[10], *bq2 = (const float*)d_in[11];
    const float* Wk2 = (const float*)d_in[12], *bk2 = (const float*)d_in[13];
    const float* Wv2 = (const float*)d_in[14], *bv2 = (const float*)d_in[15];
    const float* Ws2 = (const float*)d_in[16], *bs2 = (const float*)d_in[17];

    char* ws = (char*)d_ws;
    int* deg    = (int*)(ws + WS_DEG);
    int* cursor = (int*)(ws + WS_CURSOR);
    int* off    = (int*)(ws + WS_OFF);
    int* aux    = (int*)(ws + WS_AUX);
    int* esrc   = (int*)(ws + WS_ESRC);
    ushort_t* wt = (ushort_t*)(ws + WS_WT);
    ushort_t* xb = (ushort_t*)(ws + WS_XB);
    ushort_t* hb = (ushort_t*)(ws + WS_HB);
    ushort_t* q = (ushort_t*)(ws + WS_Q);
    ushort_t* k = (ushort_t*)(ws + WS_K);
    ushort_t* v = (ushort_t*)(ws + WS_V);
    ushort_t* s = (ushort_t*)(ws + WS_S);
    float* out = (float*)d_out;

    // pre-convert x and transpose weights
    cvt_k<<<(N_NODES * FD / 4 + 255) / 256, 256, 0, stream>>>(x, xb, N_NODES * FD / 4);
    wt_k<<<8, 256, 0, stream>>>(Wq1, Wk1, Wv1, Ws1, Wq2, Wk2, Wv2, Ws2, wt);

    // CSR build (same graph for both layers)
    hipMemsetAsync(ws + WS_DEG, 0, 400000, stream);   // deg + cursor
    hist_k<<<(N_EDGES + 255) / 256, 256, 0, stream>>>(ei, deg, N_EDGES);
    const int sblocks = (N_NODES + 255) / 256;        // 196
    scan1_k<<<sblocks, 256, 0, stream>>>(deg, off, aux, N_NODES);
    scan2_k<<<1, 256, 0, stream>>>(aux, off, sblocks, N_NODES, N_EDGES);
    scan3_k<<<sblocks, 256, 0, stream>>>(off, aux, N_NODES);
    scatter_k<<<(N_EDGES + 255) / 256, 256, 0, stream>>>(ei, off, cursor, esrc, N_EDGES);

    const int gblocks = (N_NODES + 63) / 64;          // 782
    const int attn_blocks = (N_NODES + 3) / 4;

    // layer 1
    gemm_mfma_k<<<gblocks, 256, 0, stream>>>(xb, wt, bq1, bk1, bv1, bs1,
                                             q, k, v, s, N_NODES);
    attn_k<<<attn_blocks, 256, 0, stream>>>(q, k, v, s, off, esrc, hb, nullptr,
                                            1, 1, N_NODES);

    // layer 2
    gemm_mfma_k<<<gblocks, 256, 0, stream>>>(hb, wt + 4 * FD * FD, bq2, bk2, bv2, bs2,
                                             q, k, v, s, N_NODES);
    attn_k<<<attn_blocks, 256, 0, stream>>>(q, k, v, s, off, esrc, nullptr, out,
                                            0, 0, N_NODES);
}

// Round 5
// 366.385 us; speedup vs baseline: 1.2868x; 1.2868x over previous
//
#include <hip/hip_runtime.h>
#include <math.h>

#define N_NODES 50000
#define N_EDGES 800000
#define FD 128

// ---- workspace layout (bytes) ----
#define WS_DEG    0u          // int[N]
#define WS_CURSOR 200000u     // int[N]
#define WS_OFF    400000u     // int[N+1]
#define WS_AUX    600320u     // int[256]
#define WS_ESRC   601600u     // int[E] -> ends 3801600
#define WS_WT     3801600u    // bf16[8*128*128] -> ends 4063744
#define WS_HB     16863744u   // bf16[N*128] -> 29663744
#define WS_Q      29663744u   // bf16[N*128]
#define WS_K      42463744u
#define WS_V      55263744u
#define WS_S      68063744u   // ends 80863744 (~81 MB)

typedef unsigned short ushort_t;
typedef unsigned int uint_t;
typedef __attribute__((ext_vector_type(8))) short short8;
typedef __attribute__((ext_vector_type(4))) float floatx4;

__device__ __forceinline__ ushort_t f2bf(float f) {
    uint_t u = __float_as_uint(f);
    return (ushort_t)((u + 0x7FFFu + ((u >> 16) & 1u)) >> 16);   // RNE
}
__device__ __forceinline__ float bf2f_lo(uint_t u) { return __uint_as_float(u << 16); }
__device__ __forceinline__ float bf2f_hi(uint_t u) { return __uint_as_float(u & 0xFFFF0000u); }

// ---------------- W -> W^T bf16 (8 matrices, one block each) ----------------
__global__ __launch_bounds__(256) void wt_k(
    const float* __restrict__ W0, const float* __restrict__ W1,
    const float* __restrict__ W2, const float* __restrict__ W3,
    const float* __restrict__ W4, const float* __restrict__ W5,
    const float* __restrict__ W6, const float* __restrict__ W7,
    ushort_t* __restrict__ Wt)
{
    const int m = blockIdx.x;
    const float* W = (m==0)?W0:(m==1)?W1:(m==2)?W2:(m==3)?W3:(m==4)?W4:(m==5)?W5:(m==6)?W6:W7;
    ushort_t* O = Wt + m * (FD * FD);
    #pragma unroll
    for (int it = 0; it < 16; ++it) {
        int i = threadIdx.x + it * 256;       // 0..4095
        int n = i & 127, k4 = (i >> 7) << 2;  // k4 in {0,4,...,124}
        ushort_t p[4];
        p[0] = f2bf(W[(k4 + 0) * FD + n]);
        p[1] = f2bf(W[(k4 + 1) * FD + n]);
        p[2] = f2bf(W[(k4 + 2) * FD + n]);
        p[3] = f2bf(W[(k4 + 3) * FD + n]);
        *(ushort4*)(O + n * FD + k4) = *(ushort4*)p;   // Wt[n][k]
    }
}

// ---------------- CSR build ----------------
__global__ void hist_k(const int* __restrict__ ei, int* __restrict__ deg, int E) {
    int e = blockIdx.x * blockDim.x + threadIdx.x;
    if (e < E) atomicAdd(&deg[ei[E + e]], 1);   // ei[E+e] = dst
}

__global__ __launch_bounds__(256) void scan1_k(const int* __restrict__ deg,
                                               int* __restrict__ off,
                                               int* __restrict__ aux, int n) {
    __shared__ int sbuf[256];
    int tid = threadIdx.x;
    int idx = blockIdx.x * 256 + tid;
    int val = (idx < n) ? deg[idx] : 0;
    sbuf[tid] = val;
    __syncthreads();
    #pragma unroll
    for (int d = 1; d < 256; d <<= 1) {
        int t = (tid >= d) ? sbuf[tid - d] : 0;
        __syncthreads();
        sbuf[tid] += t;
        __syncthreads();
    }
    int incl = sbuf[tid];
    if (idx < n) off[idx] = incl - val;
    if (tid == 255) aux[blockIdx.x] = incl;
}

__global__ __launch_bounds__(256) void scan2_k(int* __restrict__ aux,
                                               int* __restrict__ off,
                                               int nblocks, int n, int total) {
    __shared__ int sbuf[256];
    int tid = threadIdx.x;
    int val = (tid < nblocks) ? aux[tid] : 0;
    sbuf[tid] = val;
    __syncthreads();
    #pragma unroll
    for (int d = 1; d < 256; d <<= 1) {
        int t = (tid >= d) ? sbuf[tid - d] : 0;
        __syncthreads();
        sbuf[tid] += t;
        __syncthreads();
    }
    if (tid < nblocks) aux[tid] = sbuf[tid] - val;
    if (tid == 0) off[n] = total;
}

__global__ __launch_bounds__(256) void scan3_k(int* __restrict__ off,
                                               const int* __restrict__ aux, int n) {
    int idx = blockIdx.x * 256 + threadIdx.x;
    if (idx < n) off[idx] += aux[blockIdx.x];
}

__global__ void scatter_k(const int* __restrict__ ei, const int* __restrict__ off,
                          int* __restrict__ cursor, int* __restrict__ esrc, int E) {
    int e = blockIdx.x * blockDim.x + threadIdx.x;
    if (e < E) {
        int d = ei[E + e];
        int pos = off[d] + atomicAdd(&cursor[d], 1);
        esrc[pos] = ei[e];                            // ei[e] = src
    }
}

// ---------------- MFMA bf16 GEMM: O_m = X @ W_m + b_m, m=0..3 ----------------
// grid ceil(N/64), 256 thr (4 waves). Block stages one 64x128 bf16 X tile in LDS
// (converting fp32 on the fly for layer 1), hoists A-frags to regs, then loops
// 4 matrices: stage W^T[m] into LDS (straight copy, no transpose), 32 MFMA,
// epilogue through LDS for coalesced 16B stores.
__global__ __launch_bounds__(256) void gemm_mfma_k(
    const void* __restrict__ Xin, int x_is_fp32,
    const ushort_t* __restrict__ Wt,
    const float* __restrict__ b0, const float* __restrict__ b1,
    const float* __restrict__ b2, const float* __restrict__ b3,
    ushort_t* __restrict__ O0, ushort_t* __restrict__ O1,
    ushort_t* __restrict__ O2, ushort_t* __restrict__ O3, int N)
{
    __shared__ ushort_t As[64][136];    // X tile; reused as C tile in epilogue
    __shared__ ushort_t Bs[128][136];   // W^T tile
    const int tid = threadIdx.x;
    const int row0 = blockIdx.x * 64;

    // ---- stage X tile ----
    if (x_is_fp32) {
        const float* Xf = (const float*)Xin;
        #pragma unroll
        for (int it = 0; it < 8; ++it) {
            int i = tid + it * 256;          // 2048 float4 chunks
            int r = i >> 5, c4 = (i & 31) * 4;
            int gr = row0 + r;
            float4 xv = make_float4(0.f, 0.f, 0.f, 0.f);
            if (gr < N) xv = *(const float4*)(Xf + (size_t)gr * FD + c4);
            ushort_t p[4] = {f2bf(xv.x), f2bf(xv.y), f2bf(xv.z), f2bf(xv.w)};
            *(ushort4*)(&As[r][c4]) = *(ushort4*)p;
        }
    } else {
        const ushort_t* Xb = (const ushort_t*)Xin;
        #pragma unroll
        for (int it = 0; it < 4; ++it) {
            int i = tid + it * 256;          // 1024 x 16B chunks
            int r = i >> 4, c8 = (i & 15) * 8;
            int gr = row0 + r;
            uint4 val = make_uint4(0, 0, 0, 0);
            if (gr < N) val = *(const uint4*)(Xb + (size_t)gr * FD + c8);
            *(uint4*)(&As[r][c8]) = val;
        }
    }
    __syncthreads();

    const int wid = tid >> 6, lane = tid & 63;
    const int quad = lane >> 4, col_l = lane & 15;
    const int ar = wid * 16 + col_l;

    // ---- hoist A fragments (invariant across the 4 matrices) ----
    short8 afr[4];
    #pragma unroll
    for (int ks = 0; ks < 4; ++ks)
        afr[ks] = *(const short8*)(&As[ar][ks * 32 + quad * 8]);

    #pragma unroll 1
    for (int m = 0; m < 4; ++m) {
        const ushort_t* Wm = Wt + m * (FD * FD);
        const float* B = (m == 0) ? b0 : (m == 1) ? b1 : (m == 2) ? b2 : b3;
        ushort_t* O = (m == 0) ? O0 : (m == 1) ? O1 : (m == 2) ? O2 : O3;

        // stage Bs = W^T[m] (straight copy, coalesced, padded rows)
        #pragma unroll
        for (int it = 0; it < 8; ++it) {
            int i = tid + it * 256;          // 2048 x 16B chunks
            int r = i >> 4, c8 = (i & 15) * 8;
            *(uint4*)(&Bs[r][c8]) = *(const uint4*)(Wm + (size_t)r * FD + c8);
        }
        __syncthreads();   // Bs ready (also: prev-m C-tile reads finished)

        floatx4 acc[8];
        #pragma unroll
        for (int nt = 0; nt < 8; ++nt) acc[nt] = (floatx4){0.f, 0.f, 0.f, 0.f};

        #pragma unroll
        for (int ks = 0; ks < 4; ++ks) {
            const int kb = ks * 32 + quad * 8;
            #pragma unroll
            for (int nt = 0; nt < 8; ++nt) {
                short8 b = *(const short8*)(&Bs[nt * 16 + col_l][kb]);
                acc[nt] = __builtin_amdgcn_mfma_f32_16x16x32_bf16(afr[ks], b, acc[nt], 0, 0, 0);
            }
        }

        // C -> LDS (reuse As), add bias, then coalesced global stores
        #pragma unroll
        for (int nt = 0; nt < 8; ++nt) {
            const int col = nt * 16 + col_l;
            const float bv = B[col];
            #pragma unroll
            for (int r = 0; r < 4; ++r)
                As[wid * 16 + quad * 4 + r][col] = f2bf(acc[nt][r] + bv);
        }
        __syncthreads();   // C tile ready; Bs free for next m

        #pragma unroll
        for (int it = 0; it < 4; ++it) {
            int i = tid + it * 256;          // 1024 x 16B chunks
            int r = i >> 4, c8 = (i & 15) * 8;
            int gr = row0 + r;
            if (gr < N) *(uint4*)(O + (size_t)gr * FD + c8) = *(const uint4*)(&As[r][c8]);
        }
        // next iteration's first __syncthreads() orders C-reads vs next C-writes
    }
}

// ---------------- per-dst attention (16-lane edge groups, no-max softmax) ----------------
__global__ __launch_bounds__(256) void attn_k(
    const ushort_t* __restrict__ q, const ushort_t* __restrict__ k,
    const ushort_t* __restrict__ v, const ushort_t* __restrict__ sp,
    const int* __restrict__ off, const int* __restrict__ esrc,
    ushort_t* __restrict__ out_bf, float* __restrict__ out_f,
    int relu, int bf16out, int N)
{
    const int wid = threadIdx.x >> 6;
    const int lane = threadIdx.x & 63;
    const int g = lane >> 4;         // edge group 0..3
    const int j = lane & 15;         // lane within group
    const int dst = blockIdx.x * 4 + wid;
    if (dst >= N) return;

    const int beg = off[dst];
    const int end = off[dst + 1];
    const int f0 = j * 8;

    const uint4 qu = *(const uint4*)(q + ((size_t)dst << 7) + f0);
    float qf[8];
    qf[0] = bf2f_lo(qu.x); qf[1] = bf2f_hi(qu.x);
    qf[2] = bf2f_lo(qu.y); qf[3] = bf2f_hi(qu.y);
    qf[4] = bf2f_lo(qu.z); qf[5] = bf2f_hi(qu.z);
    qf[6] = bf2f_lo(qu.w); qf[7] = bf2f_hi(qu.w);

    const float scale = 0.08838834764831845f;   // 1/sqrt(128)
    float l = 0.f;
    float acc[8];
    #pragma unroll
    for (int i = 0; i < 8; ++i) acc[i] = 0.f;

    const int last = end - 1;
    for (int base = beg; base < end; base += 8) {
        const int e0 = base + g;
        const int e1 = base + 4 + g;
        const int i0 = (e0 <= last) ? e0 : last;
        const int i1 = (e1 <= last) ? e1 : last;
        const int s0 = esrc[i0];
        const int s1 = esrc[i1];

        const uint4 k0 = *(const uint4*)(k + ((size_t)s0 << 7) + f0);
        const uint4 k1 = *(const uint4*)(k + ((size_t)s1 << 7) + f0);

        float p0 = qf[0] * bf2f_lo(k0.x);
        p0 = fmaf(qf[1], bf2f_hi(k0.x), p0);
        p0 = fmaf(qf[2], bf2f_lo(k0.y), p0);
        p0 = fmaf(qf[3], bf2f_hi(k0.y), p0);
        p0 = fmaf(qf[4], bf2f_lo(k0.z), p0);
        p0 = fmaf(qf[5], bf2f_hi(k0.z), p0);
        p0 = fmaf(qf[6], bf2f_lo(k0.w), p0);
        p0 = fmaf(qf[7], bf2f_hi(k0.w), p0);

        float p1 = qf[0] * bf2f_lo(k1.x);
        p1 = fmaf(qf[1], bf2f_hi(k1.x), p1);
        p1 = fmaf(qf[2], bf2f_lo(k1.y), p1);
        p1 = fmaf(qf[3], bf2f_hi(k1.y), p1);
        p1 = fmaf(qf[4], bf2f_lo(k1.z), p1);
        p1 = fmaf(qf[5], bf2f_hi(k1.z), p1);
        p1 = fmaf(qf[6], bf2f_lo(k1.w), p1);
        p1 = fmaf(qf[7], bf2f_hi(k1.w), p1);

        #pragma unroll
        for (int i = 1; i <= 8; i <<= 1) {
            p0 += __shfl_xor(p0, i, 64);
            p1 += __shfl_xor(p1, i, 64);
        }

        float w0 = __expf(p0 * scale);
        float w1 = __expf(p1 * scale);
        if (e0 > last) w0 = 0.f;
        if (e1 > last) w1 = 0.f;

        const uint4 v0 = *(const uint4*)(v + ((size_t)s0 << 7) + f0);
        const uint4 v1 = *(const uint4*)(v + ((size_t)s1 << 7) + f0);

        l += w0 + w1;
        acc[0] = fmaf(w0, bf2f_lo(v0.x), fmaf(w1, bf2f_lo(v1.x), acc[0]));
        acc[1] = fmaf(w0, bf2f_hi(v0.x), fmaf(w1, bf2f_hi(v1.x), acc[1]));
        acc[2] = fmaf(w0, bf2f_lo(v0.y), fmaf(w1, bf2f_lo(v1.y), acc[2]));
        acc[3] = fmaf(w0, bf2f_hi(v0.y), fmaf(w1, bf2f_hi(v1.y), acc[3]));
        acc[4] = fmaf(w0, bf2f_lo(v0.z), fmaf(w1, bf2f_lo(v1.z), acc[4]));
        acc[5] = fmaf(w0, bf2f_hi(v0.z), fmaf(w1, bf2f_hi(v1.z), acc[5]));
        acc[6] = fmaf(w0, bf2f_lo(v0.w), fmaf(w1, bf2f_lo(v1.w), acc[6]));
        acc[7] = fmaf(w0, bf2f_hi(v0.w), fmaf(w1, bf2f_hi(v1.w), acc[7]));
    }

    #pragma unroll
    for (int i = 0; i < 8; ++i) {
        acc[i] += __shfl_xor(acc[i], 16, 64);
        acc[i] += __shfl_xor(acc[i], 32, 64);
    }
    l += __shfl_xor(l, 16, 64);
    l += __shfl_xor(l, 32, 64);

    const float inv = 1.0f / ((l == 0.f) ? 1.f : l);
    const int fo = f0 + g * 2;                          // lane stores 2 feats
    const uint_t su = *(const uint_t*)(sp + ((size_t)dst << 7) + fo);
    float ox = acc[g * 2]     * inv + bf2f_lo(su);
    float oy = acc[g * 2 + 1] * inv + bf2f_hi(su);
    if (relu) { ox = fmaxf(ox, 0.f); oy = fmaxf(oy, 0.f); }
    if (bf16out) {
        ushort_t p2[2] = {f2bf(ox), f2bf(oy)};
        *(uint_t*)(out_bf + ((size_t)dst << 7) + fo) = *(uint_t*)p2;
    } else {
        *(float2*)(out_f + ((size_t)dst << 7) + fo) = make_float2(ox, oy);
    }
}

// ---------------- launch ----------------
extern "C" void kernel_launch(void* const* d_in, const int* in_sizes, int n_in,
                              void* d_out, int out_size, void* d_ws, size_t ws_size,
                              hipStream_t stream) {
    const float* x  = (const float*)d_in[0];
    const int*   ei = (const int*)d_in[1];   // [2,E]: row0=src, row1=dst
    const float* Wq1 = (const float*)d_in[2],  *bq1 = (const float*)d_in[3];
    const float* Wk1 = (const float*)d_in[4],  *bk1 = (const float*)d_in[5];
    const float* Wv1 = (const float*)d_in[6],  *bv1 = (const float*)d_in[7];
    const float* Ws1 = (const float*)d_in[8],  *bs1 = (const float*)d_in[9];
    const float* Wq2 = (const float*)d_in[10], *bq2 = (const float*)d_in[11];
    const float* Wk2 = (const float*)d_in[12], *bk2 = (const float*)d_in[13];
    const float* Wv2 = (const float*)d_in[14], *bv2 = (const float*)d_in[15];
    const float* Ws2 = (const float*)d_in[16], *bs2 = (const float*)d_in[17];

    char* ws = (char*)d_ws;
    int* deg    = (int*)(ws + WS_DEG);
    int* cursor = (int*)(ws + WS_CURSOR);
    int* off    = (int*)(ws + WS_OFF);
    int* aux    = (int*)(ws + WS_AUX);
    int* esrc   = (int*)(ws + WS_ESRC);
    ushort_t* wt = (ushort_t*)(ws + WS_WT);
    ushort_t* hb = (ushort_t*)(ws + WS_HB);
    ushort_t* q = (ushort_t*)(ws + WS_Q);
    ushort_t* k = (ushort_t*)(ws + WS_K);
    ushort_t* v = (ushort_t*)(ws + WS_V);
    ushort_t* s = (ushort_t*)(ws + WS_S);
    float* out = (float*)d_out;

    // transpose weights to bf16 W^T (L2-resident, 256 KB)
    wt_k<<<8, 256, 0, stream>>>(Wq1, Wk1, Wv1, Ws1, Wq2, Wk2, Wv2, Ws2, wt);

    // CSR build (same graph for both layers)
    hipMemsetAsync(ws + WS_DEG, 0, 400000, stream);   // deg + cursor
    hist_k<<<(N_EDGES + 255) / 256, 256, 0, stream>>>(ei, deg, N_EDGES);
    const int sblocks = (N_NODES + 255) / 256;        // 196
    scan1_k<<<sblocks, 256, 0, stream>>>(deg, off, aux, N_NODES);
    scan2_k<<<1, 256, 0, stream>>>(aux, off, sblocks, N_NODES, N_EDGES);
    scan3_k<<<sblocks, 256, 0, stream>>>(off, aux, N_NODES);
    scatter_k<<<(N_EDGES + 255) / 256, 256, 0, stream>>>(ei, off, cursor, esrc, N_EDGES);

    const int gblocks = (N_NODES + 63) / 64;          // 782
    const int attn_blocks = (N_NODES + 3) / 4;

    // layer 1 (fp32 x, converted during staging)
    gemm_mfma_k<<<gblocks, 256, 0, stream>>>(x, 1, wt, bq1, bk1, bv1, bs1,
                                             q, k, v, s, N_NODES);
    attn_k<<<attn_blocks, 256, 0, stream>>>(q, k, v, s, off, esrc, hb, nullptr,
                                            1, 1, N_NODES);

    // layer 2 (bf16 h)
    gemm_mfma_k<<<gblocks, 256, 0, stream>>>(hb, 0, wt + 4 * FD * FD, bq2, bk2, bv2, bs2,
                                             q, k, v, s, N_NODES);
    attn_k<<<attn_blocks, 256, 0, stream>>>(q, k, v, s, off, esrc, nullptr, out,
                                            0, 0, N_NODES);
}

// Round 6
// 354.226 us; speedup vs baseline: 1.3309x; 1.0343x over previous
//
#include <hip/hip_runtime.h>
#include <math.h>

#define N_NODES 50000
#define N_EDGES 800000
#define FD 128

// ---- workspace layout (bytes) ----
#define WS_DEG    0u          // int[N]
#define WS_CURSOR 200000u     // int[N]
#define WS_OFF    400000u     // int[N+1]
#define WS_AUX    600320u     // int[256]
#define WS_ESRC   601600u     // int[E] -> ends 3801600
#define WS_WT     3801600u    // bf16[8*128*128] -> ends 4063744
#define WS_HB     16863744u   // bf16[N*128] -> 29663744
#define WS_Q      29663744u   // bf16[N*128]
#define WS_K      42463744u   // fp8[N*128] (6.4 MB; region has 12.8 MB slack)
#define WS_V      55263744u   // bf16[N*128]
#define WS_S      68063744u   // bf16[N*128], ends 80863744 (~81 MB)

typedef unsigned short ushort_t;
typedef unsigned int uint_t;
typedef unsigned char uchar_t;
typedef __attribute__((ext_vector_type(8))) short short8;
typedef __attribute__((ext_vector_type(4))) float floatx4;
typedef __attribute__((ext_vector_type(2))) float floatx2;

__device__ __forceinline__ ushort_t f2bf(float f) {
    uint_t u = __float_as_uint(f);
    return (ushort_t)((u + 0x7FFFu + ((u >> 16) & 1u)) >> 16);   // RNE
}
__device__ __forceinline__ float bf2f_lo(uint_t u) { return __uint_as_float(u << 16); }
__device__ __forceinline__ float bf2f_hi(uint_t u) { return __uint_as_float(u & 0xFFFF0000u); }

// ---------------- W -> W^T bf16 (8 matrices x 8 column-slices) ----------------
__global__ __launch_bounds__(256) void wt_k(
    const float* __restrict__ W0, const float* __restrict__ W1,
    const float* __restrict__ W2, const float* __restrict__ W3,
    const float* __restrict__ W4, const float* __restrict__ W5,
    const float* __restrict__ W6, const float* __restrict__ W7,
    ushort_t* __restrict__ Wt)
{
    const int m = blockIdx.x >> 3;
    const int sl = blockIdx.x & 7;
    const float* W = (m==0)?W0:(m==1)?W1:(m==2)?W2:(m==3)?W3:(m==4)?W4:(m==5)?W5:(m==6)?W6:W7;
    ushort_t* O = Wt + m * (FD * FD);
    #pragma unroll
    for (int it = 0; it < 2; ++it) {
        int i = threadIdx.x + it * 256 + sl * 512;   // 0..4095
        int n = i & 127, k4 = (i >> 7) << 2;
        ushort_t p[4];
        p[0] = f2bf(W[(k4 + 0) * FD + n]);
        p[1] = f2bf(W[(k4 + 1) * FD + n]);
        p[2] = f2bf(W[(k4 + 2) * FD + n]);
        p[3] = f2bf(W[(k4 + 3) * FD + n]);
        *(ushort4*)(O + n * FD + k4) = *(ushort4*)p;   // Wt[n][k]
    }
}

// ---------------- CSR build ----------------
__global__ void hist_k(const int* __restrict__ ei, int* __restrict__ deg, int E) {
    int e = blockIdx.x * blockDim.x + threadIdx.x;
    if (e < E) atomicAdd(&deg[ei[E + e]], 1);   // ei[E+e] = dst
}

__global__ __launch_bounds__(256) void scan1_k(const int* __restrict__ deg,
                                               int* __restrict__ off,
                                               int* __restrict__ aux, int n) {
    __shared__ int sbuf[256];
    int tid = threadIdx.x;
    int idx = blockIdx.x * 256 + tid;
    int val = (idx < n) ? deg[idx] : 0;
    sbuf[tid] = val;
    __syncthreads();
    #pragma unroll
    for (int d = 1; d < 256; d <<= 1) {
        int t = (tid >= d) ? sbuf[tid - d] : 0;
        __syncthreads();
        sbuf[tid] += t;
        __syncthreads();
    }
    int incl = sbuf[tid];
    if (idx < n) off[idx] = incl - val;
    if (tid == 255) aux[blockIdx.x] = incl;
}

__global__ __launch_bounds__(256) void scan2_k(int* __restrict__ aux,
                                               int* __restrict__ off,
                                               int nblocks, int n, int total) {
    __shared__ int sbuf[256];
    int tid = threadIdx.x;
    int val = (tid < nblocks) ? aux[tid] : 0;
    sbuf[tid] = val;
    __syncthreads();
    #pragma unroll
    for (int d = 1; d < 256; d <<= 1) {
        int t = (tid >= d) ? sbuf[tid - d] : 0;
        __syncthreads();
        sbuf[tid] += t;
        __syncthreads();
    }
    if (tid < nblocks) aux[tid] = sbuf[tid] - val;
    if (tid == 0) off[n] = total;
}

__global__ __launch_bounds__(256) void scan3_k(int* __restrict__ off,
                                               const int* __restrict__ aux, int n) {
    int idx = blockIdx.x * 256 + threadIdx.x;
    if (idx < n) off[idx] += aux[blockIdx.x];
}

__global__ void scatter_k(const int* __restrict__ ei, const int* __restrict__ off,
                          int* __restrict__ cursor, int* __restrict__ esrc, int E) {
    int e = blockIdx.x * blockDim.x + threadIdx.x;
    if (e < E) {
        int d = ei[E + e];
        int pos = off[d] + atomicAdd(&cursor[d], 1);
        esrc[pos] = ei[e];                            // ei[e] = src
    }
}

// ---------------- MFMA bf16 GEMM: O_m = X @ W_m + b_m, m=0..3 ----------------
// grid ceil(N/128), 256 thr (4 waves). Block stages one 128x128 bf16 X tile
// (fp32->bf16 on the fly for layer 1), hoists 8 A-frags to regs (2 m-tiles x
// 4 k-steps per wave), then loops 4 matrices: stage W^T[m] to LDS, 64 MFMA per
// wave, C through LDS for coalesced stores. k output (m==1) stored as fp8-e4m3.
__global__ __launch_bounds__(256) void gemm_mfma_k(
    const void* __restrict__ Xin, int x_is_fp32,
    const ushort_t* __restrict__ Wt,
    const float* __restrict__ b0, const float* __restrict__ b1,
    const float* __restrict__ b2, const float* __restrict__ b3,
    ushort_t* __restrict__ Oq, uchar_t* __restrict__ Ok8,
    ushort_t* __restrict__ Ov, ushort_t* __restrict__ Os, int N)
{
    __shared__ ushort_t As[128][136];   // X tile; reused as C tile
    __shared__ ushort_t Bs[128][136];   // W^T tile
    const int tid = threadIdx.x;
    const int row0 = blockIdx.x * 128;

    // ---- stage X tile ----
    if (x_is_fp32) {
        const float* Xf = (const float*)Xin;
        #pragma unroll
        for (int it = 0; it < 16; ++it) {
            int i = tid + it * 256;          // 4096 float4 chunks
            int r = i >> 5, c4 = (i & 31) * 4;
            int gr = row0 + r;
            float4 xv = make_float4(0.f, 0.f, 0.f, 0.f);
            if (gr < N) xv = *(const float4*)(Xf + (size_t)gr * FD + c4);
            ushort_t p[4] = {f2bf(xv.x), f2bf(xv.y), f2bf(xv.z), f2bf(xv.w)};
            *(ushort4*)(&As[r][c4]) = *(ushort4*)p;
        }
    } else {
        const ushort_t* Xb = (const ushort_t*)Xin;
        #pragma unroll
        for (int it = 0; it < 8; ++it) {
            int i = tid + it * 256;          // 2048 x 16B chunks
            int r = i >> 4, c8 = (i & 15) * 8;
            int gr = row0 + r;
            uint4 val = make_uint4(0, 0, 0, 0);
            if (gr < N) val = *(const uint4*)(Xb + (size_t)gr * FD + c8);
            *(uint4*)(&As[r][c8]) = val;
        }
    }
    __syncthreads();

    const int wid = tid >> 6, lane = tid & 63;
    const int quad = lane >> 4, col_l = lane & 15;

    // ---- hoist A fragments: wave owns rows [wid*32, wid*32+32) ----
    short8 afr[2][4];
    #pragma unroll
    for (int mt = 0; mt < 2; ++mt)
        #pragma unroll
        for (int ks = 0; ks < 4; ++ks)
            afr[mt][ks] = *(const short8*)(&As[wid * 32 + mt * 16 + col_l][ks * 32 + quad * 8]);

    #pragma unroll 1
    for (int m = 0; m < 4; ++m) {
        const ushort_t* Wm = Wt + m * (FD * FD);
        const float* B = (m == 0) ? b0 : (m == 1) ? b1 : (m == 2) ? b2 : b3;

        // stage Bs = W^T[m] (straight copy, coalesced, padded rows)
        #pragma unroll
        for (int it = 0; it < 8; ++it) {
            int i = tid + it * 256;          // 2048 x 16B chunks
            int r = i >> 4, c8 = (i & 15) * 8;
            *(uint4*)(&Bs[r][c8]) = *(const uint4*)(Wm + (size_t)r * FD + c8);
        }
        __syncthreads();   // Bs ready; also orders prev C-reads vs new C-writes

        floatx4 acc[2][8];
        #pragma unroll
        for (int mt = 0; mt < 2; ++mt)
            #pragma unroll
            for (int nt = 0; nt < 8; ++nt) acc[mt][nt] = (floatx4){0.f, 0.f, 0.f, 0.f};

        #pragma unroll
        for (int ks = 0; ks < 4; ++ks) {
            const int kb = ks * 32 + quad * 8;
            #pragma unroll
            for (int nt = 0; nt < 8; ++nt) {
                short8 b = *(const short8*)(&Bs[nt * 16 + col_l][kb]);
                acc[0][nt] = __builtin_amdgcn_mfma_f32_16x16x32_bf16(afr[0][ks], b, acc[0][nt], 0, 0, 0);
                acc[1][nt] = __builtin_amdgcn_mfma_f32_16x16x32_bf16(afr[1][ks], b, acc[1][nt], 0, 0, 0);
            }
        }

        // C -> LDS (reuse As; wave writes only its own 32 rows), add bias
        #pragma unroll
        for (int nt = 0; nt < 8; ++nt) {
            const int col = nt * 16 + col_l;
            const float bv = B[col];
            #pragma unroll
            for (int mt = 0; mt < 2; ++mt)
                #pragma unroll
                for (int r = 0; r < 4; ++r)
                    As[wid * 32 + mt * 16 + quad * 4 + r][col] = f2bf(acc[mt][nt][r] + bv);
        }
        __syncthreads();   // C tile ready (also: Bs free for next m after this)

        if (m == 1) {
            // k output: bf16 C tile -> fp8 e4m3, 8B per lane-chunk
            #pragma unroll
            for (int it = 0; it < 8; ++it) {
                int i = tid + it * 256;      // 2048 chunks of 8 cols
                int r = i >> 4, c8 = (i & 15) * 8;
                int gr = row0 + r;
                if (gr < N) {
                    uint4 cb = *(const uint4*)(&As[r][c8]);
                    int lo = __builtin_amdgcn_cvt_pk_fp8_f32(bf2f_lo(cb.x), bf2f_hi(cb.x), 0, false);
                    lo = __builtin_amdgcn_cvt_pk_fp8_f32(bf2f_lo(cb.y), bf2f_hi(cb.y), lo, true);
                    int hi = __builtin_amdgcn_cvt_pk_fp8_f32(bf2f_lo(cb.z), bf2f_hi(cb.z), 0, false);
                    hi = __builtin_amdgcn_cvt_pk_fp8_f32(bf2f_lo(cb.w), bf2f_hi(cb.w), hi, true);
                    *(uint2*)(Ok8 + (size_t)gr * FD + c8) = make_uint2((uint_t)lo, (uint_t)hi);
                }
            }
        } else {
            ushort_t* O = (m == 0) ? Oq : (m == 2) ? Ov : Os;
            #pragma unroll
            for (int it = 0; it < 8; ++it) {
                int i = tid + it * 256;      // 2048 x 16B chunks
                int r = i >> 4, c8 = (i & 15) * 8;
                int gr = row0 + r;
                if (gr < N) *(uint4*)(O + (size_t)gr * FD + c8) = *(const uint4*)(&As[r][c8]);
            }
        }
        // next iteration's post-staging __syncthreads orders C-reads vs next C-writes
    }
}

// ---------------- per-dst attention (16-lane edge groups, fp8 k, no-max softmax) ----------------
__global__ __launch_bounds__(256) void attn_k(
    const ushort_t* __restrict__ q, const uchar_t* __restrict__ k8,
    const ushort_t* __restrict__ v, const ushort_t* __restrict__ sp,
    const int* __restrict__ off, const int* __restrict__ esrc,
    ushort_t* __restrict__ out_bf, float* __restrict__ out_f,
    int relu, int bf16out, int N)
{
    const int wid = threadIdx.x >> 6;
    const int lane = threadIdx.x & 63;
    const int g = lane >> 4;         // edge group 0..3
    const int j = lane & 15;         // lane within group
    const int dst = blockIdx.x * 4 + wid;
    if (dst >= N) return;

    const int beg = off[dst];
    const int end = off[dst + 1];
    const int f0 = j * 8;

    const uint4 qu = *(const uint4*)(q + ((size_t)dst << 7) + f0);
    float qf[8];
    qf[0] = bf2f_lo(qu.x); qf[1] = bf2f_hi(qu.x);
    qf[2] = bf2f_lo(qu.y); qf[3] = bf2f_hi(qu.y);
    qf[4] = bf2f_lo(qu.z); qf[5] = bf2f_hi(qu.z);
    qf[6] = bf2f_lo(qu.w); qf[7] = bf2f_hi(qu.w);

    const float scale = 0.08838834764831845f;   // 1/sqrt(128)
    float l = 0.f;
    float acc[8];
    #pragma unroll
    for (int i = 0; i < 8; ++i) acc[i] = 0.f;

    const int last = end - 1;
    for (int base = beg; base < end; base += 8) {
        const int e0 = base + g;
        const int e1 = base + 4 + g;
        const int i0 = (e0 <= last) ? e0 : last;
        const int i1 = (e1 <= last) ? e1 : last;
        const int s0 = esrc[i0];
        const int s1 = esrc[i1];

        const uint2 k0 = *(const uint2*)(k8 + (size_t)s0 * FD + f0);   // 8 fp8
        const uint2 k1 = *(const uint2*)(k8 + (size_t)s1 * FD + f0);

        floatx2 ka = __builtin_amdgcn_cvt_pk_f32_fp8(k0.x, false);
        floatx2 kb = __builtin_amdgcn_cvt_pk_f32_fp8(k0.x, true);
        floatx2 kc = __builtin_amdgcn_cvt_pk_f32_fp8(k0.y, false);
        floatx2 kd = __builtin_amdgcn_cvt_pk_f32_fp8(k0.y, true);
        float p0 = qf[0] * ka.x;
        p0 = fmaf(qf[1], ka.y, p0);
        p0 = fmaf(qf[2], kb.x, p0);
        p0 = fmaf(qf[3], kb.y, p0);
        p0 = fmaf(qf[4], kc.x, p0);
        p0 = fmaf(qf[5], kc.y, p0);
        p0 = fmaf(qf[6], kd.x, p0);
        p0 = fmaf(qf[7], kd.y, p0);

        floatx2 ke = __builtin_amdgcn_cvt_pk_f32_fp8(k1.x, false);
        floatx2 kf = __builtin_amdgcn_cvt_pk_f32_fp8(k1.x, true);
        floatx2 kg = __builtin_amdgcn_cvt_pk_f32_fp8(k1.y, false);
        floatx2 kh = __builtin_amdgcn_cvt_pk_f32_fp8(k1.y, true);
        float p1 = qf[0] * ke.x;
        p1 = fmaf(qf[1], ke.y, p1);
        p1 = fmaf(qf[2], kf.x, p1);
        p1 = fmaf(qf[3], kf.y, p1);
        p1 = fmaf(qf[4], kg.x, p1);
        p1 = fmaf(qf[5], kg.y, p1);
        p1 = fmaf(qf[6], kh.x, p1);
        p1 = fmaf(qf[7], kh.y, p1);

        #pragma unroll
        for (int i = 1; i <= 8; i <<= 1) {
            p0 += __shfl_xor(p0, i, 64);
            p1 += __shfl_xor(p1, i, 64);
        }

        float w0 = __expf(p0 * scale);
        float w1 = __expf(p1 * scale);
        if (e0 > last) w0 = 0.f;
        if (e1 > last) w1 = 0.f;

        const uint4 v0 = *(const uint4*)(v + ((size_t)s0 << 7) + f0);
        const uint4 v1 = *(const uint4*)(v + ((size_t)s1 << 7) + f0);

        l += w0 + w1;
        acc[0] = fmaf(w0, bf2f_lo(v0.x), fmaf(w1, bf2f_lo(v1.x), acc[0]));
        acc[1] = fmaf(w0, bf2f_hi(v0.x), fmaf(w1, bf2f_hi(v1.x), acc[1]));
        acc[2] = fmaf(w0, bf2f_lo(v0.y), fmaf(w1, bf2f_lo(v1.y), acc[2]));
        acc[3] = fmaf(w0, bf2f_hi(v0.y), fmaf(w1, bf2f_hi(v1.y), acc[3]));
        acc[4] = fmaf(w0, bf2f_lo(v0.z), fmaf(w1, bf2f_lo(v1.z), acc[4]));
        acc[5] = fmaf(w0, bf2f_hi(v0.z), fmaf(w1, bf2f_hi(v1.z), acc[5]));
        acc[6] = fmaf(w0, bf2f_lo(v0.w), fmaf(w1, bf2f_lo(v1.w), acc[6]));
        acc[7] = fmaf(w0, bf2f_hi(v0.w), fmaf(w1, bf2f_hi(v1.w), acc[7]));
    }

    #pragma unroll
    for (int i = 0; i < 8; ++i) {
        acc[i] += __shfl_xor(acc[i], 16, 64);
        acc[i] += __shfl_xor(acc[i], 32, 64);
    }
    l += __shfl_xor(l, 16, 64);
    l += __shfl_xor(l, 32, 64);

    const float inv = 1.0f / ((l == 0.f) ? 1.f : l);
    const int fo = f0 + g * 2;                          // lane stores 2 feats
    const uint_t su = *(const uint_t*)(sp + ((size_t)dst << 7) + fo);
    float ox = acc[g * 2]     * inv + bf2f_lo(su);
    float oy = acc[g * 2 + 1] * inv + bf2f_hi(su);
    if (relu) { ox = fmaxf(ox, 0.f); oy = fmaxf(oy, 0.f); }
    if (bf16out) {
        ushort_t p2[2] = {f2bf(ox), f2bf(oy)};
        *(uint_t*)(out_bf + ((size_t)dst << 7) + fo) = *(uint_t*)p2;
    } else {
        *(float2*)(out_f + ((size_t)dst << 7) + fo) = make_float2(ox, oy);
    }
}

// ---------------- launch ----------------
extern "C" void kernel_launch(void* const* d_in, const int* in_sizes, int n_in,
                              void* d_out, int out_size, void* d_ws, size_t ws_size,
                              hipStream_t stream) {
    const float* x  = (const float*)d_in[0];
    const int*   ei = (const int*)d_in[1];   // [2,E]: row0=src, row1=dst
    const float* Wq1 = (const float*)d_in[2],  *bq1 = (const float*)d_in[3];
    const float* Wk1 = (const float*)d_in[4],  *bk1 = (const float*)d_in[5];
    const float* Wv1 = (const float*)d_in[6],  *bv1 = (const float*)d_in[7];
    const float* Ws1 = (const float*)d_in[8],  *bs1 = (const float*)d_in[9];
    const float* Wq2 = (const float*)d_in[10], *bq2 = (const float*)d_in[11];
    const float* Wk2 = (const float*)d_in[12], *bk2 = (const float*)d_in[13];
    const float* Wv2 = (const float*)d_in[14], *bv2 = (const float*)d_in[15];
    const float* Ws2 = (const float*)d_in[16], *bs2 = (const float*)d_in[17];

    char* ws = (char*)d_ws;
    int* deg    = (int*)(ws + WS_DEG);
    int* cursor = (int*)(ws + WS_CURSOR);
    int* off    = (int*)(ws + WS_OFF);
    int* aux    = (int*)(ws + WS_AUX);
    int* esrc   = (int*)(ws + WS_ESRC);
    ushort_t* wt = (ushort_t*)(ws + WS_WT);
    ushort_t* hb = (ushort_t*)(ws + WS_HB);
    ushort_t* q  = (ushort_t*)(ws + WS_Q);
    uchar_t*  k8 = (uchar_t*)(ws + WS_K);
    ushort_t* v  = (ushort_t*)(ws + WS_V);
    ushort_t* s  = (ushort_t*)(ws + WS_S);
    float* out = (float*)d_out;

    // transpose weights to bf16 W^T (L2-resident, 256 KB)
    wt_k<<<64, 256, 0, stream>>>(Wq1, Wk1, Wv1, Ws1, Wq2, Wk2, Wv2, Ws2, wt);

    // CSR build (same graph for both layers)
    hipMemsetAsync(ws + WS_DEG, 0, 400000, stream);   // deg + cursor
    hist_k<<<(N_EDGES + 255) / 256, 256, 0, stream>>>(ei, deg, N_EDGES);
    const int sblocks = (N_NODES + 255) / 256;        // 196
    scan1_k<<<sblocks, 256, 0, stream>>>(deg, off, aux, N_NODES);
    scan2_k<<<1, 256, 0, stream>>>(aux, off, sblocks, N_NODES, N_EDGES);
    scan3_k<<<sblocks, 256, 0, stream>>>(off, aux, N_NODES);
    scatter_k<<<(N_EDGES + 255) / 256, 256, 0, stream>>>(ei, off, cursor, esrc, N_EDGES);

    const int gblocks = (N_NODES + 127) / 128;        // 391
    const int attn_blocks = (N_NODES + 3) / 4;

    // layer 1 (fp32 x, converted during staging)
    gemm_mfma_k<<<gblocks, 256, 0, stream>>>(x, 1, wt, bq1, bk1, bv1, bs1,
                                             q, k8, v, s, N_NODES);
    attn_k<<<attn_blocks, 256, 0, stream>>>(q, k8, v, s, off, esrc, hb, nullptr,
                                            1, 1, N_NODES);

    // layer 2 (bf16 h)
    gemm_mfma_k<<<gblocks, 256, 0, stream>>>(hb, 0, wt + 4 * FD * FD, bq2, bk2, bv2, bs2,
                                             q, k8, v, s, N_NODES);
    attn_k<<<attn_blocks, 256, 0, stream>>>(q, k8, v, s, off, esrc, nullptr, out,
                                            0, 0, N_NODES);
}

// Round 7
// 341.219 us; speedup vs baseline: 1.3817x; 1.0381x over previous
//
#include <hip/hip_runtime.h>
#include <math.h>

#define N_NODES 50000
#define N_EDGES 800000
#define FD 128

// ---- workspace layout (bytes) ----
// memset range [0, 201600): deg + lookback comb flags + ticket
#define WS_DEG    0u          // int[N]
#define WS_COMB   200000u     // u64[196] lookback (flag<<32 | value)
#define WS_TICKET 201568u     // int
#define WS_CURSOR 201600u     // int[N] (written by scan, no memset needed)
#define WS_OFF    401600u     // int[N+1] -> 601604, pad to 601728
#define WS_ESRC   601728u     // int[E] -> 3801728
#define WS_WT     3801728u    // bf16[8*128*128] -> 4063872
#define WS_HB     16863744u   // bf16[N*128]
#define WS_Q      29663744u   // bf16[N*128]
#define WS_K      42463744u   // fp8[N*128]
#define WS_V      55263744u   // bf16[N*128]
#define WS_S      68063744u   // bf16[N*128], ends 80863744

typedef unsigned short ushort_t;
typedef unsigned int uint_t;
typedef unsigned char uchar_t;
typedef unsigned long long ull_t;
typedef __attribute__((ext_vector_type(8))) short short8;
typedef __attribute__((ext_vector_type(4))) float floatx4;
typedef __attribute__((ext_vector_type(2))) float floatx2;

__device__ __forceinline__ ushort_t f2bf(float f) {
    uint_t u = __float_as_uint(f);
    return (ushort_t)((u + 0x7FFFu + ((u >> 16) & 1u)) >> 16);   // RNE
}
__device__ __forceinline__ float bf2f_lo(uint_t u) { return __uint_as_float(u << 16); }
__device__ __forceinline__ float bf2f_hi(uint_t u) { return __uint_as_float(u & 0xFFFF0000u); }

// ---------------- prep: W->W^T bf16 (blocks 0..63) + degree histogram (64..845) ----------------
__global__ __launch_bounds__(256) void prep_k(
    const float* __restrict__ W0, const float* __restrict__ W1,
    const float* __restrict__ W2, const float* __restrict__ W3,
    const float* __restrict__ W4, const float* __restrict__ W5,
    const float* __restrict__ W6, const float* __restrict__ W7,
    ushort_t* __restrict__ Wt,
    const int* __restrict__ ei, int* __restrict__ deg)
{
    if (blockIdx.x < 64) {
        const int m = blockIdx.x >> 3;
        const int sl = blockIdx.x & 7;
        const float* W = (m==0)?W0:(m==1)?W1:(m==2)?W2:(m==3)?W3:(m==4)?W4:(m==5)?W5:(m==6)?W6:W7;
        ushort_t* O = Wt + m * (FD * FD);
        #pragma unroll
        for (int it = 0; it < 2; ++it) {
            int i = threadIdx.x + it * 256 + sl * 512;   // 0..4095
            int n = i & 127, k4 = (i >> 7) << 2;
            ushort_t p[4];
            p[0] = f2bf(W[(k4 + 0) * FD + n]);
            p[1] = f2bf(W[(k4 + 1) * FD + n]);
            p[2] = f2bf(W[(k4 + 2) * FD + n]);
            p[3] = f2bf(W[(k4 + 3) * FD + n]);
            *(ushort4*)(O + n * FD + k4) = *(ushort4*)p;   // Wt[n][k]
        }
    } else {
        const int b = blockIdx.x - 64;                    // 0..781
        const int e0 = b * 1024 + threadIdx.x * 4;
        if (e0 < N_EDGES) {                               // E % 4 == 0
            int4 d4 = *(const int4*)(ei + N_EDGES + e0);  // dst row
            atomicAdd(&deg[d4.x], 1);
            atomicAdd(&deg[d4.y], 1);
            atomicAdd(&deg[d4.z], 1);
            atomicAdd(&deg[d4.w], 1);
        }
    }
}

// ---------------- single-pass decoupled-lookback exclusive scan ----------------
// 196 blocks x 256. Ticket-ordered bids => predecessors are already running
// (deadlock-free even without co-residency; 196 < 256 CUs anyway).
// Writes off[] AND cursor[] (= off), and off[n] = total.
__global__ __launch_bounds__(256) void scan_lb_k(
    const int* __restrict__ deg, int* __restrict__ off, int* __restrict__ cursor,
    ull_t* __restrict__ comb, int* __restrict__ ticket, int n, int total)
{
    __shared__ int sbuf[256];
    __shared__ int s_bid, s_prefix;
    const int tid = threadIdx.x;
    if (tid == 0) s_bid = atomicAdd(ticket, 1);
    __syncthreads();
    const int bid = s_bid;
    const int idx = bid * 256 + tid;
    int val = (idx < n) ? deg[idx] : 0;
    sbuf[tid] = val;
    __syncthreads();
    #pragma unroll
    for (int d = 1; d < 256; d <<= 1) {
        int t = (tid >= d) ? sbuf[tid - d] : 0;
        __syncthreads();
        sbuf[tid] += t;
        __syncthreads();
    }
    const int incl = sbuf[tid];
    const int btot = sbuf[255];

    if (tid == 0) {
        int prefix = 0;
        if (bid == 0) {
            atomicExch(&comb[0], ((ull_t)2 << 32) | (uint_t)btot);
        } else {
            atomicExch(&comb[bid], ((ull_t)1 << 32) | (uint_t)btot);
            int j = bid - 1;
            while (j >= 0) {
                ull_t c;
                do { c = atomicAdd(&comb[j], 0ULL); } while ((c >> 32) == 0);
                prefix += (int)(c & 0xFFFFFFFFu);
                if ((c >> 32) == 2) break;
                --j;
            }
            atomicExch(&comb[bid], ((ull_t)2 << 32) | (uint_t)(prefix + btot));
        }
        s_prefix = prefix;
    }
    __syncthreads();
    const int excl = s_prefix + incl - val;
    if (idx < n) { off[idx] = excl; cursor[idx] = excl; }
    if (idx == 0) off[n] = total;
}

// ---------------- MFMA bf16 GEMM (+ optional fused edge scatter) ----------------
// grid ceil(N/64)=782, 256 thr (4 waves). 64-row X tile (3 blocks/CU), hoisted
// A-frags, per-matrix Bs staging from precomputed W^T, C through LDS for
// coalesced stores; k output (m==1) stored fp8-e4m3.
// do_scatter: block b also CSR-scatters edges [b*1024, b*1024+1024) — the
// atomics/scattered stores hide under MFMA; consumer (attn) is a later kernel.
__global__ __launch_bounds__(256) void gemm_mfma_k(
    const void* __restrict__ Xin, int x_is_fp32,
    const ushort_t* __restrict__ Wt,
    const float* __restrict__ b0, const float* __restrict__ b1,
    const float* __restrict__ b2, const float* __restrict__ b3,
    ushort_t* __restrict__ Oq, uchar_t* __restrict__ Ok8,
    ushort_t* __restrict__ Ov, ushort_t* __restrict__ Os,
    const int* __restrict__ ei, int* __restrict__ cursor,
    int* __restrict__ esrc, int do_scatter, int N)
{
    __shared__ ushort_t As[64][136];    // X tile; reused as C tile
    __shared__ ushort_t Bs[128][136];   // W^T tile
    const int tid = threadIdx.x;
    const int row0 = blockIdx.x * 64;

    if (do_scatter) {
        const int e0 = blockIdx.x * 1024 + tid * 4;
        if (e0 < N_EDGES) {
            int4 s4 = *(const int4*)(ei + e0);
            int4 d4 = *(const int4*)(ei + N_EDGES + e0);
            int p0 = atomicAdd(&cursor[d4.x], 1); esrc[p0] = s4.x;
            int p1 = atomicAdd(&cursor[d4.y], 1); esrc[p1] = s4.y;
            int p2 = atomicAdd(&cursor[d4.z], 1); esrc[p2] = s4.z;
            int p3 = atomicAdd(&cursor[d4.w], 1); esrc[p3] = s4.w;
        }
    }

    // ---- stage X tile ----
    if (x_is_fp32) {
        const float* Xf = (const float*)Xin;
        #pragma unroll
        for (int it = 0; it < 8; ++it) {
            int i = tid + it * 256;          // 2048 float4 chunks
            int r = i >> 5, c4 = (i & 31) * 4;
            int gr = row0 + r;
            float4 xv = make_float4(0.f, 0.f, 0.f, 0.f);
            if (gr < N) xv = *(const float4*)(Xf + (size_t)gr * FD + c4);
            ushort_t p[4] = {f2bf(xv.x), f2bf(xv.y), f2bf(xv.z), f2bf(xv.w)};
            *(ushort4*)(&As[r][c4]) = *(ushort4*)p;
        }
    } else {
        const ushort_t* Xb = (const ushort_t*)Xin;
        #pragma unroll
        for (int it = 0; it < 4; ++it) {
            int i = tid + it * 256;          // 1024 x 16B chunks
            int r = i >> 4, c8 = (i & 15) * 8;
            int gr = row0 + r;
            uint4 val = make_uint4(0, 0, 0, 0);
            if (gr < N) val = *(const uint4*)(Xb + (size_t)gr * FD + c8);
            *(uint4*)(&As[r][c8]) = val;
        }
    }
    __syncthreads();

    const int wid = tid >> 6, lane = tid & 63;
    const int quad = lane >> 4, col_l = lane & 15;
    const int ar = wid * 16 + col_l;

    // ---- hoist A fragments (invariant across the 4 matrices) ----
    short8 afr[4];
    #pragma unroll
    for (int ks = 0; ks < 4; ++ks)
        afr[ks] = *(const short8*)(&As[ar][ks * 32 + quad * 8]);

    #pragma unroll 1
    for (int m = 0; m < 4; ++m) {
        const ushort_t* Wm = Wt + m * (FD * FD);
        const float* B = (m == 0) ? b0 : (m == 1) ? b1 : (m == 2) ? b2 : b3;

        // stage Bs = W^T[m] (straight copy, coalesced, padded rows)
        #pragma unroll
        for (int it = 0; it < 8; ++it) {
            int i = tid + it * 256;          // 2048 x 16B chunks
            int r = i >> 4, c8 = (i & 15) * 8;
            *(uint4*)(&Bs[r][c8]) = *(const uint4*)(Wm + (size_t)r * FD + c8);
        }
        __syncthreads();   // Bs ready; also orders prev C-tile reads vs new C-writes

        floatx4 acc[8];
        #pragma unroll
        for (int nt = 0; nt < 8; ++nt) acc[nt] = (floatx4){0.f, 0.f, 0.f, 0.f};

        #pragma unroll
        for (int ks = 0; ks < 4; ++ks) {
            const int kb = ks * 32 + quad * 8;
            #pragma unroll
            for (int nt = 0; nt < 8; ++nt) {
                short8 b = *(const short8*)(&Bs[nt * 16 + col_l][kb]);
                acc[nt] = __builtin_amdgcn_mfma_f32_16x16x32_bf16(afr[ks], b, acc[nt], 0, 0, 0);
            }
        }

        // C -> LDS (reuse As), add bias
        #pragma unroll
        for (int nt = 0; nt < 8; ++nt) {
            const int col = nt * 16 + col_l;
            const float bv = B[col];
            #pragma unroll
            for (int r = 0; r < 4; ++r)
                As[wid * 16 + quad * 4 + r][col] = f2bf(acc[nt][r] + bv);
        }
        __syncthreads();   // C tile ready

        if (m == 1) {
            // k output: bf16 C tile -> fp8 e4m3
            #pragma unroll
            for (int it = 0; it < 4; ++it) {
                int i = tid + it * 256;      // 1024 chunks of 8 cols
                int r = i >> 4, c8 = (i & 15) * 8;
                int gr = row0 + r;
                if (gr < N) {
                    uint4 cb = *(const uint4*)(&As[r][c8]);
                    int lo = __builtin_amdgcn_cvt_pk_fp8_f32(bf2f_lo(cb.x), bf2f_hi(cb.x), 0, false);
                    lo = __builtin_amdgcn_cvt_pk_fp8_f32(bf2f_lo(cb.y), bf2f_hi(cb.y), lo, true);
                    int hi = __builtin_amdgcn_cvt_pk_fp8_f32(bf2f_lo(cb.z), bf2f_hi(cb.z), 0, false);
                    hi = __builtin_amdgcn_cvt_pk_fp8_f32(bf2f_lo(cb.w), bf2f_hi(cb.w), hi, true);
                    *(uint2*)(Ok8 + (size_t)gr * FD + c8) = make_uint2((uint_t)lo, (uint_t)hi);
                }
            }
        } else {
            ushort_t* O = (m == 0) ? Oq : (m == 2) ? Ov : Os;
            #pragma unroll
            for (int it = 0; it < 4; ++it) {
                int i = tid + it * 256;      // 1024 x 16B chunks
                int r = i >> 4, c8 = (i & 15) * 8;
                int gr = row0 + r;
                if (gr < N) *(uint4*)(O + (size_t)gr * FD + c8) = *(const uint4*)(&As[r][c8]);
            }
        }
        // next iteration's post-staging __syncthreads orders C-reads vs next C-writes
    }
}

// ---------------- per-dst attention (16-lane edge groups, fp8 k, no-max softmax) ----------------
__global__ __launch_bounds__(256) void attn_k(
    const ushort_t* __restrict__ q, const uchar_t* __restrict__ k8,
    const ushort_t* __restrict__ v, const ushort_t* __restrict__ sp,
    const int* __restrict__ off, const int* __restrict__ esrc,
    ushort_t* __restrict__ out_bf, float* __restrict__ out_f,
    int relu, int bf16out, int N)
{
    const int wid = threadIdx.x >> 6;
    const int lane = threadIdx.x & 63;
    const int g = lane >> 4;         // edge group 0..3
    const int j = lane & 15;         // lane within group
    const int dst = blockIdx.x * 4 + wid;
    if (dst >= N) return;

    const int beg = off[dst];
    const int end = off[dst + 1];
    const int f0 = j * 8;

    const uint4 qu = *(const uint4*)(q + ((size_t)dst << 7) + f0);
    float qf[8];
    qf[0] = bf2f_lo(qu.x); qf[1] = bf2f_hi(qu.x);
    qf[2] = bf2f_lo(qu.y); qf[3] = bf2f_hi(qu.y);
    qf[4] = bf2f_lo(qu.z); qf[5] = bf2f_hi(qu.z);
    qf[6] = bf2f_lo(qu.w); qf[7] = bf2f_hi(qu.w);

    const float scale = 0.08838834764831845f;   // 1/sqrt(128)
    float l = 0.f;
    float acc[8];
    #pragma unroll
    for (int i = 0; i < 8; ++i) acc[i] = 0.f;

    const int last = end - 1;
    for (int base = beg; base < end; base += 8) {
        const int e0 = base + g;
        const int e1 = base + 4 + g;
        const int i0 = (e0 <= last) ? e0 : last;
        const int i1 = (e1 <= last) ? e1 : last;
        const int s0 = esrc[i0];
        const int s1 = esrc[i1];

        const uint2 k0 = *(const uint2*)(k8 + (size_t)s0 * FD + f0);   // 8 fp8
        const uint2 k1 = *(const uint2*)(k8 + (size_t)s1 * FD + f0);

        floatx2 ka = __builtin_amdgcn_cvt_pk_f32_fp8(k0.x, false);
        floatx2 kb = __builtin_amdgcn_cvt_pk_f32_fp8(k0.x, true);
        floatx2 kc = __builtin_amdgcn_cvt_pk_f32_fp8(k0.y, false);
        floatx2 kd = __builtin_amdgcn_cvt_pk_f32_fp8(k0.y, true);
        float p0 = qf[0] * ka.x;
        p0 = fmaf(qf[1], ka.y, p0);
        p0 = fmaf(qf[2], kb.x, p0);
        p0 = fmaf(qf[3], kb.y, p0);
        p0 = fmaf(qf[4], kc.x, p0);
        p0 = fmaf(qf[5], kc.y, p0);
        p0 = fmaf(qf[6], kd.x, p0);
        p0 = fmaf(qf[7], kd.y, p0);

        floatx2 ke = __builtin_amdgcn_cvt_pk_f32_fp8(k1.x, false);
        floatx2 kf = __builtin_amdgcn_cvt_pk_f32_fp8(k1.x, true);
        floatx2 kg = __builtin_amdgcn_cvt_pk_f32_fp8(k1.y, false);
        floatx2 kh = __builtin_amdgcn_cvt_pk_f32_fp8(k1.y, true);
        float p1 = qf[0] * ke.x;
        p1 = fmaf(qf[1], ke.y, p1);
        p1 = fmaf(qf[2], kf.x, p1);
        p1 = fmaf(qf[3], kf.y, p1);
        p1 = fmaf(qf[4], kg.x, p1);
        p1 = fmaf(qf[5], kg.y, p1);
        p1 = fmaf(qf[6], kh.x, p1);
        p1 = fmaf(qf[7], kh.y, p1);

        #pragma unroll
        for (int i = 1; i <= 8; i <<= 1) {
            p0 += __shfl_xor(p0, i, 64);
            p1 += __shfl_xor(p1, i, 64);
        }

        float w0 = __expf(p0 * scale);
        float w1 = __expf(p1 * scale);
        if (e0 > last) w0 = 0.f;
        if (e1 > last) w1 = 0.f;

        const uint4 v0 = *(const uint4*)(v + ((size_t)s0 << 7) + f0);
        const uint4 v1 = *(const uint4*)(v + ((size_t)s1 << 7) + f0);

        l += w0 + w1;
        acc[0] = fmaf(w0, bf2f_lo(v0.x), fmaf(w1, bf2f_lo(v1.x), acc[0]));
        acc[1] = fmaf(w0, bf2f_hi(v0.x), fmaf(w1, bf2f_hi(v1.x), acc[1]));
        acc[2] = fmaf(w0, bf2f_lo(v0.y), fmaf(w1, bf2f_lo(v1.y), acc[2]));
        acc[3] = fmaf(w0, bf2f_hi(v0.y), fmaf(w1, bf2f_hi(v1.y), acc[3]));
        acc[4] = fmaf(w0, bf2f_lo(v0.z), fmaf(w1, bf2f_lo(v1.z), acc[4]));
        acc[5] = fmaf(w0, bf2f_hi(v0.z), fmaf(w1, bf2f_hi(v1.z), acc[5]));
        acc[6] = fmaf(w0, bf2f_lo(v0.w), fmaf(w1, bf2f_lo(v1.w), acc[6]));
        acc[7] = fmaf(w0, bf2f_hi(v0.w), fmaf(w1, bf2f_hi(v1.w), acc[7]));
    }

    #pragma unroll
    for (int i = 0; i < 8; ++i) {
        acc[i] += __shfl_xor(acc[i], 16, 64);
        acc[i] += __shfl_xor(acc[i], 32, 64);
    }
    l += __shfl_xor(l, 16, 64);
    l += __shfl_xor(l, 32, 64);

    const float inv = 1.0f / ((l == 0.f) ? 1.f : l);
    const int fo = f0 + g * 2;                          // lane stores 2 feats
    const uint_t su = *(const uint_t*)(sp + ((size_t)dst << 7) + fo);
    float ox = acc[g * 2]     * inv + bf2f_lo(su);
    float oy = acc[g * 2 + 1] * inv + bf2f_hi(su);
    if (relu) { ox = fmaxf(ox, 0.f); oy = fmaxf(oy, 0.f); }
    if (bf16out) {
        ushort_t p2[2] = {f2bf(ox), f2bf(oy)};
        *(uint_t*)(out_bf + ((size_t)dst << 7) + fo) = *(uint_t*)p2;
    } else {
        *(float2*)(out_f + ((size_t)dst << 7) + fo) = make_float2(ox, oy);
    }
}

// ---------------- launch ----------------
extern "C" void kernel_launch(void* const* d_in, const int* in_sizes, int n_in,
                              void* d_out, int out_size, void* d_ws, size_t ws_size,
                              hipStream_t stream) {
    const float* x  = (const float*)d_in[0];
    const int*   ei = (const int*)d_in[1];   // [2,E]: row0=src, row1=dst
    const float* Wq1 = (const float*)d_in[2],  *bq1 = (const float*)d_in[3];
    const float* Wk1 = (const float*)d_in[4],  *bk1 = (const float*)d_in[5];
    const float* Wv1 = (const float*)d_in[6],  *bv1 = (const float*)d_in[7];
    const float* Ws1 = (const float*)d_in[8],  *bs1 = (const float*)d_in[9];
    const float* Wq2 = (const float*)d_in[10], *bq2 = (const float*)d_in[11];
    const float* Wk2 = (const float*)d_in[12], *bk2 = (const float*)d_in[13];
    const float* Wv2 = (const float*)d_in[14], *bv2 = (const float*)d_in[15];
    const float* Ws2 = (const float*)d_in[16], *bs2 = (const float*)d_in[17];

    char* ws = (char*)d_ws;
    int* deg     = (int*)(ws + WS_DEG);
    ull_t* comb  = (ull_t*)(ws + WS_COMB);
    int* ticket  = (int*)(ws + WS_TICKET);
    int* cursor  = (int*)(ws + WS_CURSOR);
    int* off     = (int*)(ws + WS_OFF);
    int* esrc    = (int*)(ws + WS_ESRC);
    ushort_t* wt = (ushort_t*)(ws + WS_WT);
    ushort_t* hb = (ushort_t*)(ws + WS_HB);
    ushort_t* q  = (ushort_t*)(ws + WS_Q);
    uchar_t*  k8 = (uchar_t*)(ws + WS_K);
    ushort_t* v  = (ushort_t*)(ws + WS_V);
    ushort_t* s  = (ushort_t*)(ws + WS_S);
    float* out = (float*)d_out;

    const int gblocks = (N_NODES + 63) / 64;          // 782
    const int attn_blocks = (N_NODES + 3) / 4;        // 12500
    const int sblocks = (N_NODES + 255) / 256;        // 196

    // zero deg + lookback state
    hipMemsetAsync(ws + WS_DEG, 0, 201600, stream);

    // fused: weight transpose (blocks 0..63) + degree histogram (64..845)
    prep_k<<<64 + gblocks, 256, 0, stream>>>(Wq1, Wk1, Wv1, Ws1, Wq2, Wk2, Wv2, Ws2,
                                             wt, ei, deg);

    // single-pass scan -> off[] and cursor[]
    scan_lb_k<<<sblocks, 256, 0, stream>>>(deg, off, cursor, comb, ticket,
                                           N_NODES, N_EDGES);

    // layer 1 GEMM (fp32 x) + fused CSR scatter (hidden under MFMA)
    gemm_mfma_k<<<gblocks, 256, 0, stream>>>(x, 1, wt, bq1, bk1, bv1, bs1,
                                             q, k8, v, s, ei, cursor, esrc, 1, N_NODES);
    attn_k<<<attn_blocks, 256, 0, stream>>>(q, k8, v, s, off, esrc, hb, nullptr,
                                            1, 1, N_NODES);

    // layer 2
    gemm_mfma_k<<<gblocks, 256, 0, stream>>>(hb, 0, wt + 4 * FD * FD, bq2, bk2, bv2, bs2,
                                             q, k8, v, s, ei, cursor, esrc, 0, N_NODES);
    attn_k<<<attn_blocks, 256, 0, stream>>>(q, k8, v, s, off, esrc, nullptr, out,
                                            0, 0, N_NODES);
}

// Round 8
// 315.396 us; speedup vs baseline: 1.4948x; 1.0819x over previous
//
#include <hip/hip_runtime.h>
#include <math.h>

#define N_NODES 50000
#define N_EDGES 800000
#define FD 128

// ---- workspace layout (bytes) ----
#define WS_DEG    0u          // int[N]   (deg + cursor memset together, 400KB)
#define WS_CURSOR 200000u     // int[N]
#define WS_OFF    400000u     // int[N+1]
#define WS_AUX    600320u     // int[256]
#define WS_ESRC   601600u     // int[E] -> 3801600
#define WS_WT     3801600u    // bf16[8*128*128] -> 4063744
#define WS_HB     16863744u   // bf16[N*128]
#define WS_Q      29663744u   // bf16[N*128]
#define WS_K      42463744u   // fp8[N*128] (6.4 MB)
#define WS_V      55263744u   // fp8[N*128] (6.4 MB)
#define WS_S      68063744u   // bf16[N*128], ends 80863744

typedef unsigned short ushort_t;
typedef unsigned int uint_t;
typedef unsigned char uchar_t;
typedef __attribute__((ext_vector_type(8))) short short8;
typedef __attribute__((ext_vector_type(4))) float floatx4;
typedef __attribute__((ext_vector_type(2))) float floatx2;

__device__ __forceinline__ ushort_t f2bf(float f) {
    uint_t u = __float_as_uint(f);
    return (ushort_t)((u + 0x7FFFu + ((u >> 16) & 1u)) >> 16);   // RNE
}
__device__ __forceinline__ float bf2f_lo(uint_t u) { return __uint_as_float(u << 16); }
__device__ __forceinline__ float bf2f_hi(uint_t u) { return __uint_as_float(u & 0xFFFF0000u); }

// ---------------- prep: W->W^T bf16 (blocks 0..63) + degree histogram (64..845) ----------------
__global__ __launch_bounds__(256) void prep_k(
    const float* __restrict__ W0, const float* __restrict__ W1,
    const float* __restrict__ W2, const float* __restrict__ W3,
    const float* __restrict__ W4, const float* __restrict__ W5,
    const float* __restrict__ W6, const float* __restrict__ W7,
    ushort_t* __restrict__ Wt,
    const int* __restrict__ ei, int* __restrict__ deg)
{
    if (blockIdx.x < 64) {
        const int m = blockIdx.x >> 3;
        const int sl = blockIdx.x & 7;
        const float* W = (m==0)?W0:(m==1)?W1:(m==2)?W2:(m==3)?W3:(m==4)?W4:(m==5)?W5:(m==6)?W6:W7;
        ushort_t* O = Wt + m * (FD * FD);
        #pragma unroll
        for (int it = 0; it < 2; ++it) {
            int i = threadIdx.x + it * 256 + sl * 512;   // 0..4095
            int n = i & 127, k4 = (i >> 7) << 2;
            ushort_t p[4];
            p[0] = f2bf(W[(k4 + 0) * FD + n]);
            p[1] = f2bf(W[(k4 + 1) * FD + n]);
            p[2] = f2bf(W[(k4 + 2) * FD + n]);
            p[3] = f2bf(W[(k4 + 3) * FD + n]);
            *(ushort4*)(O + n * FD + k4) = *(ushort4*)p;   // Wt[n][k]
        }
    } else {
        const int b = blockIdx.x - 64;                    // 0..781
        const int e0 = b * 1024 + threadIdx.x * 4;
        if (e0 < N_EDGES) {                               // E % 4 == 0
            int4 d4 = *(const int4*)(ei + N_EDGES + e0);  // dst row
            atomicAdd(&deg[d4.x], 1);
            atomicAdd(&deg[d4.y], 1);
            atomicAdd(&deg[d4.z], 1);
            atomicAdd(&deg[d4.w], 1);
        }
    }
}

// ---------------- 3-kernel parallel scan ----------------
__global__ __launch_bounds__(256) void scan1_k(const int* __restrict__ deg,
                                               int* __restrict__ off,
                                               int* __restrict__ aux, int n) {
    __shared__ int sbuf[256];
    int tid = threadIdx.x;
    int idx = blockIdx.x * 256 + tid;
    int val = (idx < n) ? deg[idx] : 0;
    sbuf[tid] = val;
    __syncthreads();
    #pragma unroll
    for (int d = 1; d < 256; d <<= 1) {
        int t = (tid >= d) ? sbuf[tid - d] : 0;
        __syncthreads();
        sbuf[tid] += t;
        __syncthreads();
    }
    int incl = sbuf[tid];
    if (idx < n) off[idx] = incl - val;
    if (tid == 255) aux[blockIdx.x] = incl;
}

__global__ __launch_bounds__(256) void scan2_k(int* __restrict__ aux,
                                               int* __restrict__ off,
                                               int nblocks, int n, int total) {
    __shared__ int sbuf[256];
    int tid = threadIdx.x;
    int val = (tid < nblocks) ? aux[tid] : 0;
    sbuf[tid] = val;
    __syncthreads();
    #pragma unroll
    for (int d = 1; d < 256; d <<= 1) {
        int t = (tid >= d) ? sbuf[tid - d] : 0;
        __syncthreads();
        sbuf[tid] += t;
        __syncthreads();
    }
    if (tid < nblocks) aux[tid] = sbuf[tid] - val;
    if (tid == 0) off[n] = total;
}

__global__ __launch_bounds__(256) void scan3_k(int* __restrict__ off,
                                               const int* __restrict__ aux, int n) {
    int idx = blockIdx.x * 256 + threadIdx.x;
    if (idx < n) off[idx] += aux[blockIdx.x];
}

__global__ void scatter_k(const int* __restrict__ ei, const int* __restrict__ off,
                          int* __restrict__ cursor, int* __restrict__ esrc, int E) {
    int e = blockIdx.x * blockDim.x + threadIdx.x;
    if (e < E) {
        int d = ei[E + e];
        int pos = off[d] + atomicAdd(&cursor[d], 1);
        esrc[pos] = ei[e];                            // ei[e] = src
    }
}

// ---------------- MFMA bf16 GEMM: O_m = X @ W_m + b_m, m=0..3 ----------------
// grid ceil(N/64)=782, 256 thr (4 waves), 52 KB LDS -> 3 blocks/CU.
// Stage 64x128 X tile (fp32->bf16 on the fly for layer 1), hoist A-frags,
// loop 4 matrices: stage W^T[m] to LDS (straight copy), MFMA, C through LDS
// for coalesced stores. k (m==1) and v (m==2) outputs stored fp8-e4m3.
__global__ __launch_bounds__(256) void gemm_mfma_k(
    const void* __restrict__ Xin, int x_is_fp32,
    const ushort_t* __restrict__ Wt,
    const float* __restrict__ b0, const float* __restrict__ b1,
    const float* __restrict__ b2, const float* __restrict__ b3,
    ushort_t* __restrict__ Oq, uchar_t* __restrict__ Ok8,
    uchar_t* __restrict__ Ov8, ushort_t* __restrict__ Os, int N)
{
    __shared__ ushort_t As[64][136];    // X tile; reused as C tile
    __shared__ ushort_t Bs[128][136];   // W^T tile
    const int tid = threadIdx.x;
    const int row0 = blockIdx.x * 64;

    // ---- stage X tile ----
    if (x_is_fp32) {
        const float* Xf = (const float*)Xin;
        #pragma unroll
        for (int it = 0; it < 8; ++it) {
            int i = tid + it * 256;          // 2048 float4 chunks
            int r = i >> 5, c4 = (i & 31) * 4;
            int gr = row0 + r;
            float4 xv = make_float4(0.f, 0.f, 0.f, 0.f);
            if (gr < N) xv = *(const float4*)(Xf + (size_t)gr * FD + c4);
            ushort_t p[4] = {f2bf(xv.x), f2bf(xv.y), f2bf(xv.z), f2bf(xv.w)};
            *(ushort4*)(&As[r][c4]) = *(ushort4*)p;
        }
    } else {
        const ushort_t* Xb = (const ushort_t*)Xin;
        #pragma unroll
        for (int it = 0; it < 4; ++it) {
            int i = tid + it * 256;          // 1024 x 16B chunks
            int r = i >> 4, c8 = (i & 15) * 8;
            int gr = row0 + r;
            uint4 val = make_uint4(0, 0, 0, 0);
            if (gr < N) val = *(const uint4*)(Xb + (size_t)gr * FD + c8);
            *(uint4*)(&As[r][c8]) = val;
        }
    }
    __syncthreads();

    const int wid = tid >> 6, lane = tid & 63;
    const int quad = lane >> 4, col_l = lane & 15;
    const int ar = wid * 16 + col_l;

    // ---- hoist A fragments (invariant across the 4 matrices) ----
    short8 afr[4];
    #pragma unroll
    for (int ks = 0; ks < 4; ++ks)
        afr[ks] = *(const short8*)(&As[ar][ks * 32 + quad * 8]);

    #pragma unroll 1
    for (int m = 0; m < 4; ++m) {
        const ushort_t* Wm = Wt + m * (FD * FD);
        const float* B = (m == 0) ? b0 : (m == 1) ? b1 : (m == 2) ? b2 : b3;

        // stage Bs = W^T[m] (straight copy, coalesced, padded rows)
        #pragma unroll
        for (int it = 0; it < 8; ++it) {
            int i = tid + it * 256;          // 2048 x 16B chunks
            int r = i >> 4, c8 = (i & 15) * 8;
            *(uint4*)(&Bs[r][c8]) = *(const uint4*)(Wm + (size_t)r * FD + c8);
        }
        __syncthreads();   // Bs ready; also orders prev C-tile reads vs new C-writes

        floatx4 acc[8];
        #pragma unroll
        for (int nt = 0; nt < 8; ++nt) acc[nt] = (floatx4){0.f, 0.f, 0.f, 0.f};

        #pragma unroll
        for (int ks = 0; ks < 4; ++ks) {
            const int kb = ks * 32 + quad * 8;
            #pragma unroll
            for (int nt = 0; nt < 8; ++nt) {
                short8 b = *(const short8*)(&Bs[nt * 16 + col_l][kb]);
                acc[nt] = __builtin_amdgcn_mfma_f32_16x16x32_bf16(afr[ks], b, acc[nt], 0, 0, 0);
            }
        }

        // C -> LDS (reuse As), add bias
        #pragma unroll
        for (int nt = 0; nt < 8; ++nt) {
            const int col = nt * 16 + col_l;
            const float bv = B[col];
            #pragma unroll
            for (int r = 0; r < 4; ++r)
                As[wid * 16 + quad * 4 + r][col] = f2bf(acc[nt][r] + bv);
        }
        __syncthreads();   // C tile ready

        if (m == 1 || m == 2) {
            // k/v output: bf16 C tile -> fp8 e4m3
            uchar_t* O8 = (m == 1) ? Ok8 : Ov8;
            #pragma unroll
            for (int it = 0; it < 4; ++it) {
                int i = tid + it * 256;      // 1024 chunks of 8 cols
                int r = i >> 4, c8 = (i & 15) * 8;
                int gr = row0 + r;
                if (gr < N) {
                    uint4 cb = *(const uint4*)(&As[r][c8]);
                    int lo = __builtin_amdgcn_cvt_pk_fp8_f32(bf2f_lo(cb.x), bf2f_hi(cb.x), 0, false);
                    lo = __builtin_amdgcn_cvt_pk_fp8_f32(bf2f_lo(cb.y), bf2f_hi(cb.y), lo, true);
                    int hi = __builtin_amdgcn_cvt_pk_fp8_f32(bf2f_lo(cb.z), bf2f_hi(cb.z), 0, false);
                    hi = __builtin_amdgcn_cvt_pk_fp8_f32(bf2f_lo(cb.w), bf2f_hi(cb.w), hi, true);
                    *(uint2*)(O8 + (size_t)gr * FD + c8) = make_uint2((uint_t)lo, (uint_t)hi);
                }
            }
        } else {
            ushort_t* O = (m == 0) ? Oq : Os;
            #pragma unroll
            for (int it = 0; it < 4; ++it) {
                int i = tid + it * 256;      // 1024 x 16B chunks
                int r = i >> 4, c8 = (i & 15) * 8;
                int gr = row0 + r;
                if (gr < N) *(uint4*)(O + (size_t)gr * FD + c8) = *(const uint4*)(&As[r][c8]);
            }
        }
        // next iteration's post-staging __syncthreads orders C-reads vs next C-writes
    }
}

// ---------------- per-dst attention (16-lane edge groups, fp8 k+v, no-max softmax) ----------------
__global__ __launch_bounds__(256) void attn_k(
    const ushort_t* __restrict__ q, const uchar_t* __restrict__ k8,
    const uchar_t* __restrict__ v8, const ushort_t* __restrict__ sp,
    const int* __restrict__ off, const int* __restrict__ esrc,
    ushort_t* __restrict__ out_bf, float* __restrict__ out_f,
    int relu, int bf16out, int N)
{
    const int wid = threadIdx.x >> 6;
    const int lane = threadIdx.x & 63;
    const int g = lane >> 4;         // edge group 0..3
    const int j = lane & 15;         // lane within group
    const int dst = blockIdx.x * 4 + wid;
    if (dst >= N) return;

    const int beg = off[dst];
    const int end = off[dst + 1];
    const int f0 = j * 8;

    const uint4 qu = *(const uint4*)(q + ((size_t)dst << 7) + f0);
    float qf[8];
    qf[0] = bf2f_lo(qu.x); qf[1] = bf2f_hi(qu.x);
    qf[2] = bf2f_lo(qu.y); qf[3] = bf2f_hi(qu.y);
    qf[4] = bf2f_lo(qu.z); qf[5] = bf2f_hi(qu.z);
    qf[6] = bf2f_lo(qu.w); qf[7] = bf2f_hi(qu.w);

    const float scale = 0.08838834764831845f;   // 1/sqrt(128)
    float l = 0.f;
    float acc[8];
    #pragma unroll
    for (int i = 0; i < 8; ++i) acc[i] = 0.f;

    const int last = end - 1;
    for (int base = beg; base < end; base += 8) {
        const int e0 = base + g;
        const int e1 = base + 4 + g;
        const int i0 = (e0 <= last) ? e0 : last;
        const int i1 = (e1 <= last) ? e1 : last;
        const int s0 = esrc[i0];
        const int s1 = esrc[i1];

        const uint2 k0 = *(const uint2*)(k8 + (size_t)s0 * FD + f0);   // 8 fp8
        const uint2 k1 = *(const uint2*)(k8 + (size_t)s1 * FD + f0);

        floatx2 ka = __builtin_amdgcn_cvt_pk_f32_fp8(k0.x, false);
        floatx2 kb = __builtin_amdgcn_cvt_pk_f32_fp8(k0.x, true);
        floatx2 kc = __builtin_amdgcn_cvt_pk_f32_fp8(k0.y, false);
        floatx2 kd = __builtin_amdgcn_cvt_pk_f32_fp8(k0.y, true);
        float p0 = qf[0] * ka.x;
        p0 = fmaf(qf[1], ka.y, p0);
        p0 = fmaf(qf[2], kb.x, p0);
        p0 = fmaf(qf[3], kb.y, p0);
        p0 = fmaf(qf[4], kc.x, p0);
        p0 = fmaf(qf[5], kc.y, p0);
        p0 = fmaf(qf[6], kd.x, p0);
        p0 = fmaf(qf[7], kd.y, p0);

        floatx2 ke = __builtin_amdgcn_cvt_pk_f32_fp8(k1.x, false);
        floatx2 kf = __builtin_amdgcn_cvt_pk_f32_fp8(k1.x, true);
        floatx2 kg = __builtin_amdgcn_cvt_pk_f32_fp8(k1.y, false);
        floatx2 kh = __builtin_amdgcn_cvt_pk_f32_fp8(k1.y, true);
        float p1 = qf[0] * ke.x;
        p1 = fmaf(qf[1], ke.y, p1);
        p1 = fmaf(qf[2], kf.x, p1);
        p1 = fmaf(qf[3], kf.y, p1);
        p1 = fmaf(qf[4], kg.x, p1);
        p1 = fmaf(qf[5], kg.y, p1);
        p1 = fmaf(qf[6], kh.x, p1);
        p1 = fmaf(qf[7], kh.y, p1);

        #pragma unroll
        for (int i = 1; i <= 8; i <<= 1) {
            p0 += __shfl_xor(p0, i, 64);
            p1 += __shfl_xor(p1, i, 64);
        }

        float w0 = __expf(p0 * scale);
        float w1 = __expf(p1 * scale);
        if (e0 > last) w0 = 0.f;
        if (e1 > last) w1 = 0.f;

        const uint2 v0 = *(const uint2*)(v8 + (size_t)s0 * FD + f0);   // 8 fp8
        const uint2 v1 = *(const uint2*)(v8 + (size_t)s1 * FD + f0);

        floatx2 va = __builtin_amdgcn_cvt_pk_f32_fp8(v0.x, false);
        floatx2 vb = __builtin_amdgcn_cvt_pk_f32_fp8(v0.x, true);
        floatx2 vc = __builtin_amdgcn_cvt_pk_f32_fp8(v0.y, false);
        floatx2 vd = __builtin_amdgcn_cvt_pk_f32_fp8(v0.y, true);
        floatx2 ve = __builtin_amdgcn_cvt_pk_f32_fp8(v1.x, false);
        floatx2 vf = __builtin_amdgcn_cvt_pk_f32_fp8(v1.x, true);
        floatx2 vg = __builtin_amdgcn_cvt_pk_f32_fp8(v1.y, false);
        floatx2 vh = __builtin_amdgcn_cvt_pk_f32_fp8(v1.y, true);

        l += w0 + w1;
        acc[0] = fmaf(w0, va.x, fmaf(w1, ve.x, acc[0]));
        acc[1] = fmaf(w0, va.y, fmaf(w1, ve.y, acc[1]));
        acc[2] = fmaf(w0, vb.x, fmaf(w1, vf.x, acc[2]));
        acc[3] = fmaf(w0, vb.y, fmaf(w1, vf.y, acc[3]));
        acc[4] = fmaf(w0, vc.x, fmaf(w1, vg.x, acc[4]));
        acc[5] = fmaf(w0, vc.y, fmaf(w1, vg.y, acc[5]));
        acc[6] = fmaf(w0, vd.x, fmaf(w1, vh.x, acc[6]));
        acc[7] = fmaf(w0, vd.y, fmaf(w1, vh.y, acc[7]));
    }

    #pragma unroll
    for (int i = 0; i < 8; ++i) {
        acc[i] += __shfl_xor(acc[i], 16, 64);
        acc[i] += __shfl_xor(acc[i], 32, 64);
    }
    l += __shfl_xor(l, 16, 64);
    l += __shfl_xor(l, 32, 64);

    const float inv = 1.0f / ((l == 0.f) ? 1.f : l);
    const int fo = f0 + g * 2;                          // lane stores 2 feats
    const uint_t su = *(const uint_t*)(sp + ((size_t)dst << 7) + fo);
    float ox = acc[g * 2]     * inv + bf2f_lo(su);
    float oy = acc[g * 2 + 1] * inv + bf2f_hi(su);
    if (relu) { ox = fmaxf(ox, 0.f); oy = fmaxf(oy, 0.f); }
    if (bf16out) {
        ushort_t p2[2] = {f2bf(ox), f2bf(oy)};
        *(uint_t*)(out_bf + ((size_t)dst << 7) + fo) = *(uint_t*)p2;
    } else {
        *(float2*)(out_f + ((size_t)dst << 7) + fo) = make_float2(ox, oy);
    }
}

// ---------------- launch ----------------
extern "C" void kernel_launch(void* const* d_in, const int* in_sizes, int n_in,
                              void* d_out, int out_size, void* d_ws, size_t ws_size,
                              hipStream_t stream) {
    const float* x  = (const float*)d_in[0];
    const int*   ei = (const int*)d_in[1];   // [2,E]: row0=src, row1=dst
    const float* Wq1 = (const float*)d_in[2],  *bq1 = (const float*)d_in[3];
    const float* Wk1 = (const float*)d_in[4],  *bk1 = (const float*)d_in[5];
    const float* Wv1 = (const float*)d_in[6],  *bv1 = (const float*)d_in[7];
    const float* Ws1 = (const float*)d_in[8],  *bs1 = (const float*)d_in[9];
    const float* Wq2 = (const float*)d_in[10], *bq2 = (const float*)d_in[11];
    const float* Wk2 = (const float*)d_in[12], *bk2 = (const float*)d_in[13];
    const float* Wv2 = (const float*)d_in[14], *bv2 = (const float*)d_in[15];
    const float* Ws2 = (const float*)d_in[16], *bs2 = (const float*)d_in[17];

    char* ws = (char*)d_ws;
    int* deg     = (int*)(ws + WS_DEG);
    int* cursor  = (int*)(ws + WS_CURSOR);
    int* off     = (int*)(ws + WS_OFF);
    int* aux     = (int*)(ws + WS_AUX);
    int* esrc    = (int*)(ws + WS_ESRC);
    ushort_t* wt = (ushort_t*)(ws + WS_WT);
    ushort_t* hb = (ushort_t*)(ws + WS_HB);
    ushort_t* q  = (ushort_t*)(ws + WS_Q);
    uchar_t*  k8 = (uchar_t*)(ws + WS_K);
    uchar_t*  v8 = (uchar_t*)(ws + WS_V);
    ushort_t* s  = (ushort_t*)(ws + WS_S);
    float* out = (float*)d_out;

    const int gblocks = (N_NODES + 63) / 64;          // 782
    const int attn_blocks = (N_NODES + 3) / 4;        // 12500
    const int sblocks = (N_NODES + 255) / 256;        // 196

    // zero deg + cursor
    hipMemsetAsync(ws + WS_DEG, 0, 400000, stream);

    // fused: weight transpose (blocks 0..63) + degree histogram (64..845)
    prep_k<<<64 + gblocks, 256, 0, stream>>>(Wq1, Wk1, Wv1, Ws1, Wq2, Wk2, Wv2, Ws2,
                                             wt, ei, deg);

    // 3-kernel parallel scan -> off[]
    scan1_k<<<sblocks, 256, 0, stream>>>(deg, off, aux, N_NODES);
    scan2_k<<<1, 256, 0, stream>>>(aux, off, sblocks, N_NODES, N_EDGES);
    scan3_k<<<sblocks, 256, 0, stream>>>(off, aux, N_NODES);
    scatter_k<<<(N_EDGES + 255) / 256, 256, 0, stream>>>(ei, off, cursor, esrc, N_EDGES);

    // layer 1 (fp32 x, converted during staging)
    gemm_mfma_k<<<gblocks, 256, 0, stream>>>(x, 1, wt, bq1, bk1, bv1, bs1,
                                             q, k8, v8, s, N_NODES);
    attn_k<<<attn_blocks, 256, 0, stream>>>(q, k8, v8, s, off, esrc, hb, nullptr,
                                            1, 1, N_NODES);

    // layer 2 (bf16 h)
    gemm_mfma_k<<<gblocks, 256, 0, stream>>>(hb, 0, wt + 4 * FD * FD, bq2, bk2, bv2, bs2,
                                             q, k8, v8, s, N_NODES);
    attn_k<<<attn_blocks, 256, 0, stream>>>(q, k8, v8, s, off, esrc, nullptr, out,
                                            0, 0, N_NODES);
}

// Round 9
// 310.973 us; speedup vs baseline: 1.5161x; 1.0142x over previous
//
#include <hip/hip_runtime.h>
#include <math.h>

#define N_NODES 50000
#define N_EDGES 800000
#define FD 128

#define NBUCK 64          // buckets used: dst>>10 -> 0..48
#define BCAP  24576       // entries per bucket (mean 16384, +64 sigma)

// ---- workspace layout (bytes) ----
#define WS_DEG    0u          // int[N]     \  memset [0, 400256)
#define WS_CURSOR 200000u     // int[N]      |
#define WS_BCUR   400000u     // int[64]    /
#define WS_OFF    400256u     // int[N+1] -> 600260
#define WS_AUX    600320u     // int[256]
#define WS_ESRC   601728u     // ushort[E] -> 2201728
#define WS_WT     3801600u    // bf16[8*128*128] -> 4063744
#define WS_HB     16863744u   // bf16[N*128]; ALSO aliased as bin staging (disjoint lifetime)
#define WS_STAGE  16863744u   // uint32[64*24576] = 6.29 MB -> 23155200
#define WS_Q      29663744u   // bf16[N*128]
#define WS_K      42463744u   // fp8[N*128]
#define WS_V      55263744u   // fp8[N*128]
#define WS_S      68063744u   // bf16[N*128], ends 80863744

typedef unsigned short ushort_t;
typedef unsigned int uint_t;
typedef unsigned char uchar_t;
typedef __attribute__((ext_vector_type(8))) short short8;
typedef __attribute__((ext_vector_type(4))) float floatx4;
typedef __attribute__((ext_vector_type(2))) float floatx2;

__device__ __forceinline__ ushort_t f2bf(float f) {
    uint_t u = __float_as_uint(f);
    return (ushort_t)((u + 0x7FFFu + ((u >> 16) & 1u)) >> 16);   // RNE
}
__device__ __forceinline__ float bf2f_lo(uint_t u) { return __uint_as_float(u << 16); }
__device__ __forceinline__ float bf2f_hi(uint_t u) { return __uint_as_float(u & 0xFFFF0000u); }

// ---------------- prep: W->W^T bf16 (blocks 0..63) + edge binning + deg hist (64..) ----------------
// Pass A of the locality scatter: block bins 2048 edges by dst>>10 into per-bucket
// staging as contiguous runs (LDS hist -> one global atomicAdd per bucket), packing
// (src | dst<<16). Also accumulates the degree histogram (single read of ei).
__global__ __launch_bounds__(256) void prep_k(
    const float* __restrict__ W0, const float* __restrict__ W1,
    const float* __restrict__ W2, const float* __restrict__ W3,
    const float* __restrict__ W4, const float* __restrict__ W5,
    const float* __restrict__ W6, const float* __restrict__ W7,
    ushort_t* __restrict__ Wt,
    const int* __restrict__ ei, int* __restrict__ deg,
    int* __restrict__ bcur, uint_t* __restrict__ staging)
{
    if (blockIdx.x < 64) {
        const int m = blockIdx.x >> 3;
        const int sl = blockIdx.x & 7;
        const float* W = (m==0)?W0:(m==1)?W1:(m==2)?W2:(m==3)?W3:(m==4)?W4:(m==5)?W5:(m==6)?W6:W7;
        ushort_t* O = Wt + m * (FD * FD);
        #pragma unroll
        for (int it = 0; it < 2; ++it) {
            int i = threadIdx.x + it * 256 + sl * 512;   // 0..4095
            int n = i & 127, k4 = (i >> 7) << 2;
            ushort_t p[4];
            p[0] = f2bf(W[(k4 + 0) * FD + n]);
            p[1] = f2bf(W[(k4 + 1) * FD + n]);
            p[2] = f2bf(W[(k4 + 2) * FD + n]);
            p[3] = f2bf(W[(k4 + 3) * FD + n]);
            *(ushort4*)(O + n * FD + k4) = *(ushort4*)p;   // Wt[n][k]
        }
    } else {
        __shared__ int lhist[NBUCK];
        __shared__ int lbase[NBUCK];
        const int tid = threadIdx.x;
        const int base = (blockIdx.x - 64) * 2048 + tid * 8;   // E % 8 == 0
        if (tid < NBUCK) lhist[tid] = 0;
        __syncthreads();

        uint_t pk[8];
        int li[8];
        const bool act = (base < N_EDGES);
        if (act) {
            int4 s0 = *(const int4*)(ei + base);
            int4 s1 = *(const int4*)(ei + base + 4);
            int4 d0 = *(const int4*)(ei + N_EDGES + base);
            int4 d1 = *(const int4*)(ei + N_EDGES + base + 4);
            int srcs[8] = {s0.x, s0.y, s0.z, s0.w, s1.x, s1.y, s1.z, s1.w};
            int dsts[8] = {d0.x, d0.y, d0.z, d0.w, d1.x, d1.y, d1.z, d1.w};
            #pragma unroll
            for (int j = 0; j < 8; ++j) {
                atomicAdd(&deg[dsts[j]], 1);
                li[j] = atomicAdd(&lhist[dsts[j] >> 10], 1);
                pk[j] = (uint_t)srcs[j] | ((uint_t)dsts[j] << 16);
            }
        }
        __syncthreads();
        if (tid < NBUCK) lbase[tid] = atomicAdd(&bcur[tid], lhist[tid]);
        __syncthreads();
        if (act) {
            #pragma unroll
            for (int j = 0; j < 8; ++j) {
                int bk = pk[j] >> 26;       // dst>>10
                staging[bk * BCAP + lbase[bk] + li[j]] = pk[j];
            }
        }
    }
}

// ---------------- 3-kernel parallel scan ----------------
__global__ __launch_bounds__(256) void scan1_k(const int* __restrict__ deg,
                                               int* __restrict__ off,
                                               int* __restrict__ aux, int n) {
    __shared__ int sbuf[256];
    int tid = threadIdx.x;
    int idx = blockIdx.x * 256 + tid;
    int val = (idx < n) ? deg[idx] : 0;
    sbuf[tid] = val;
    __syncthreads();
    #pragma unroll
    for (int d = 1; d < 256; d <<= 1) {
        int t = (tid >= d) ? sbuf[tid - d] : 0;
        __syncthreads();
        sbuf[tid] += t;
        __syncthreads();
    }
    int incl = sbuf[tid];
    if (idx < n) off[idx] = incl - val;
    if (tid == 255) aux[blockIdx.x] = incl;
}

__global__ __launch_bounds__(256) void scan2_k(int* __restrict__ aux,
                                               int* __restrict__ off,
                                               int nblocks, int n, int total) {
    __shared__ int sbuf[256];
    int tid = threadIdx.x;
    int val = (tid < nblocks) ? aux[tid] : 0;
    sbuf[tid] = val;
    __syncthreads();
    #pragma unroll
    for (int d = 1; d < 256; d <<= 1) {
        int t = (tid >= d) ? sbuf[tid - d] : 0;
        __syncthreads();
        sbuf[tid] += t;
        __syncthreads();
    }
    if (tid < nblocks) aux[tid] = sbuf[tid] - val;
    if (tid == 0) off[n] = total;
}

__global__ __launch_bounds__(256) void scan3_k(int* __restrict__ off,
                                               const int* __restrict__ aux, int n) {
    int idx = blockIdx.x * 256 + threadIdx.x;
    if (idx < n) off[idx] += aux[blockIdx.x];
}

// ---------------- Pass B: per-bucket scatter into CSR (esrc window ~32 KB, L2-hot) ----------------
__global__ __launch_bounds__(256) void binscat_k(
    const uint_t* __restrict__ staging, const int* __restrict__ bcur,
    const int* __restrict__ off, int* __restrict__ cursor,
    ushort_t* __restrict__ esrc)
{
    const int b = blockIdx.x;        // bucket 0..48
    const int part = blockIdx.y;     // 0..7
    const int count = bcur[b];
    const int s = (count * part) >> 3;
    const int e = (count * (part + 1)) >> 3;
    for (int i = s + threadIdx.x; i < e; i += 256) {
        uint_t pkv = staging[b * BCAP + i];
        int src = pkv & 0xFFFFu;
        int dst = pkv >> 16;
        int pos = off[dst] + atomicAdd(&cursor[dst], 1);
        esrc[pos] = (ushort_t)src;
    }
}

// ---------------- MFMA bf16 GEMM: O_m = X @ W_m + b_m, m=0..3 ----------------
// grid ceil(N/64)=782, 256 thr (4 waves), 52 KB LDS -> 3 blocks/CU.
__global__ __launch_bounds__(256) void gemm_mfma_k(
    const void* __restrict__ Xin, int x_is_fp32,
    const ushort_t* __restrict__ Wt,
    const float* __restrict__ b0, const float* __restrict__ b1,
    const float* __restrict__ b2, const float* __restrict__ b3,
    ushort_t* __restrict__ Oq, uchar_t* __restrict__ Ok8,
    uchar_t* __restrict__ Ov8, ushort_t* __restrict__ Os, int N)
{
    __shared__ ushort_t As[64][136];    // X tile; reused as C tile
    __shared__ ushort_t Bs[128][136];   // W^T tile
    const int tid = threadIdx.x;
    const int row0 = blockIdx.x * 64;

    // ---- stage X tile ----
    if (x_is_fp32) {
        const float* Xf = (const float*)Xin;
        #pragma unroll
        for (int it = 0; it < 8; ++it) {
            int i = tid + it * 256;          // 2048 float4 chunks
            int r = i >> 5, c4 = (i & 31) * 4;
            int gr = row0 + r;
            float4 xv = make_float4(0.f, 0.f, 0.f, 0.f);
            if (gr < N) xv = *(const float4*)(Xf + (size_t)gr * FD + c4);
            ushort_t p[4] = {f2bf(xv.x), f2bf(xv.y), f2bf(xv.z), f2bf(xv.w)};
            *(ushort4*)(&As[r][c4]) = *(ushort4*)p;
        }
    } else {
        const ushort_t* Xb = (const ushort_t*)Xin;
        #pragma unroll
        for (int it = 0; it < 4; ++it) {
            int i = tid + it * 256;          // 1024 x 16B chunks
            int r = i >> 4, c8 = (i & 15) * 8;
            int gr = row0 + r;
            uint4 val = make_uint4(0, 0, 0, 0);
            if (gr < N) val = *(const uint4*)(Xb + (size_t)gr * FD + c8);
            *(uint4*)(&As[r][c8]) = val;
        }
    }
    __syncthreads();

    const int wid = tid >> 6, lane = tid & 63;
    const int quad = lane >> 4, col_l = lane & 15;
    const int ar = wid * 16 + col_l;

    // ---- hoist A fragments (invariant across the 4 matrices) ----
    short8 afr[4];
    #pragma unroll
    for (int ks = 0; ks < 4; ++ks)
        afr[ks] = *(const short8*)(&As[ar][ks * 32 + quad * 8]);

    #pragma unroll 1
    for (int m = 0; m < 4; ++m) {
        const ushort_t* Wm = Wt + m * (FD * FD);
        const float* B = (m == 0) ? b0 : (m == 1) ? b1 : (m == 2) ? b2 : b3;

        // stage Bs = W^T[m] (straight copy, coalesced, padded rows)
        #pragma unroll
        for (int it = 0; it < 8; ++it) {
            int i = tid + it * 256;          // 2048 x 16B chunks
            int r = i >> 4, c8 = (i & 15) * 8;
            *(uint4*)(&Bs[r][c8]) = *(const uint4*)(Wm + (size_t)r * FD + c8);
        }
        __syncthreads();   // Bs ready; also orders prev C-tile reads vs new C-writes

        floatx4 acc[8];
        #pragma unroll
        for (int nt = 0; nt < 8; ++nt) acc[nt] = (floatx4){0.f, 0.f, 0.f, 0.f};

        #pragma unroll
        for (int ks = 0; ks < 4; ++ks) {
            const int kb = ks * 32 + quad * 8;
            #pragma unroll
            for (int nt = 0; nt < 8; ++nt) {
                short8 b = *(const short8*)(&Bs[nt * 16 + col_l][kb]);
                acc[nt] = __builtin_amdgcn_mfma_f32_16x16x32_bf16(afr[ks], b, acc[nt], 0, 0, 0);
            }
        }

        // C -> LDS (reuse As), add bias
        #pragma unroll
        for (int nt = 0; nt < 8; ++nt) {
            const int col = nt * 16 + col_l;
            const float bv = B[col];
            #pragma unroll
            for (int r = 0; r < 4; ++r)
                As[wid * 16 + quad * 4 + r][col] = f2bf(acc[nt][r] + bv);
        }
        __syncthreads();   // C tile ready

        if (m == 1 || m == 2) {
            // k/v output: bf16 C tile -> fp8 e4m3
            uchar_t* O8 = (m == 1) ? Ok8 : Ov8;
            #pragma unroll
            for (int it = 0; it < 4; ++it) {
                int i = tid + it * 256;      // 1024 chunks of 8 cols
                int r = i >> 4, c8 = (i & 15) * 8;
                int gr = row0 + r;
                if (gr < N) {
                    uint4 cb = *(const uint4*)(&As[r][c8]);
                    int lo = __builtin_amdgcn_cvt_pk_fp8_f32(bf2f_lo(cb.x), bf2f_hi(cb.x), 0, false);
                    lo = __builtin_amdgcn_cvt_pk_fp8_f32(bf2f_lo(cb.y), bf2f_hi(cb.y), lo, true);
                    int hi = __builtin_amdgcn_cvt_pk_fp8_f32(bf2f_lo(cb.z), bf2f_hi(cb.z), 0, false);
                    hi = __builtin_amdgcn_cvt_pk_fp8_f32(bf2f_lo(cb.w), bf2f_hi(cb.w), hi, true);
                    *(uint2*)(O8 + (size_t)gr * FD + c8) = make_uint2((uint_t)lo, (uint_t)hi);
                }
            }
        } else {
            ushort_t* O = (m == 0) ? Oq : Os;
            #pragma unroll
            for (int it = 0; it < 4; ++it) {
                int i = tid + it * 256;      // 1024 x 16B chunks
                int r = i >> 4, c8 = (i & 15) * 8;
                int gr = row0 + r;
                if (gr < N) *(uint4*)(O + (size_t)gr * FD + c8) = *(const uint4*)(&As[r][c8]);
            }
        }
    }
}

// ---------------- per-dst attention (16-lane edge groups, fp8 k+v, no-max softmax) ----------------
__global__ __launch_bounds__(256) void attn_k(
    const ushort_t* __restrict__ q, const uchar_t* __restrict__ k8,
    const uchar_t* __restrict__ v8, const ushort_t* __restrict__ sp,
    const int* __restrict__ off, const ushort_t* __restrict__ esrc,
    ushort_t* __restrict__ out_bf, float* __restrict__ out_f,
    int relu, int bf16out, int N)
{
    const int wid = threadIdx.x >> 6;
    const int lane = threadIdx.x & 63;
    const int g = lane >> 4;         // edge group 0..3
    const int j = lane & 15;         // lane within group
    const int dst = blockIdx.x * 4 + wid;
    if (dst >= N) return;

    const int beg = off[dst];
    const int end = off[dst + 1];
    const int f0 = j * 8;

    const uint4 qu = *(const uint4*)(q + ((size_t)dst << 7) + f0);
    float qf[8];
    qf[0] = bf2f_lo(qu.x); qf[1] = bf2f_hi(qu.x);
    qf[2] = bf2f_lo(qu.y); qf[3] = bf2f_hi(qu.y);
    qf[4] = bf2f_lo(qu.z); qf[5] = bf2f_hi(qu.z);
    qf[6] = bf2f_lo(qu.w); qf[7] = bf2f_hi(qu.w);

    const float scale = 0.08838834764831845f;   // 1/sqrt(128)
    float l = 0.f;
    float acc[8];
    #pragma unroll
    for (int i = 0; i < 8; ++i) acc[i] = 0.f;

    const int last = end - 1;
    for (int base = beg; base < end; base += 8) {
        const int e0 = base + g;
        const int e1 = base + 4 + g;
        const int i0 = (e0 <= last) ? e0 : last;
        const int i1 = (e1 <= last) ? e1 : last;
        const int s0 = esrc[i0];
        const int s1 = esrc[i1];

        const uint2 k0 = *(const uint2*)(k8 + (size_t)s0 * FD + f0);   // 8 fp8
        const uint2 k1 = *(const uint2*)(k8 + (size_t)s1 * FD + f0);

        floatx2 ka = __builtin_amdgcn_cvt_pk_f32_fp8(k0.x, false);
        floatx2 kb = __builtin_amdgcn_cvt_pk_f32_fp8(k0.x, true);
        floatx2 kc = __builtin_amdgcn_cvt_pk_f32_fp8(k0.y, false);
        floatx2 kd = __builtin_amdgcn_cvt_pk_f32_fp8(k0.y, true);
        float p0 = qf[0] * ka.x;
        p0 = fmaf(qf[1], ka.y, p0);
        p0 = fmaf(qf[2], kb.x, p0);
        p0 = fmaf(qf[3], kb.y, p0);
        p0 = fmaf(qf[4], kc.x, p0);
        p0 = fmaf(qf[5], kc.y, p0);
        p0 = fmaf(qf[6], kd.x, p0);
        p0 = fmaf(qf[7], kd.y, p0);

        floatx2 ke = __builtin_amdgcn_cvt_pk_f32_fp8(k1.x, false);
        floatx2 kf = __builtin_amdgcn_cvt_pk_f32_fp8(k1.x, true);
        floatx2 kg = __builtin_amdgcn_cvt_pk_f32_fp8(k1.y, false);
        floatx2 kh = __builtin_amdgcn_cvt_pk_f32_fp8(k1.y, true);
        float p1 = qf[0] * ke.x;
        p1 = fmaf(qf[1], ke.y, p1);
        p1 = fmaf(qf[2], kf.x, p1);
        p1 = fmaf(qf[3], kf.y, p1);
        p1 = fmaf(qf[4], kg.x, p1);
        p1 = fmaf(qf[5], kg.y, p1);
        p1 = fmaf(qf[6], kh.x, p1);
        p1 = fmaf(qf[7], kh.y, p1);

        #pragma unroll
        for (int i = 1; i <= 8; i <<= 1) {
            p0 += __shfl_xor(p0, i, 64);
            p1 += __shfl_xor(p1, i, 64);
        }

        float w0 = __expf(p0 * scale);
        float w1 = __expf(p1 * scale);
        if (e0 > last) w0 = 0.f;
        if (e1 > last) w1 = 0.f;

        const uint2 v0 = *(const uint2*)(v8 + (size_t)s0 * FD + f0);   // 8 fp8
        const uint2 v1 = *(const uint2*)(v8 + (size_t)s1 * FD + f0);

        floatx2 va = __builtin_amdgcn_cvt_pk_f32_fp8(v0.x, false);
        floatx2 vb = __builtin_amdgcn_cvt_pk_f32_fp8(v0.x, true);
        floatx2 vc = __builtin_amdgcn_cvt_pk_f32_fp8(v0.y, false);
        floatx2 vd = __builtin_amdgcn_cvt_pk_f32_fp8(v0.y, true);
        floatx2 ve = __builtin_amdgcn_cvt_pk_f32_fp8(v1.x, false);
        floatx2 vf = __builtin_amdgcn_cvt_pk_f32_fp8(v1.x, true);
        floatx2 vg = __builtin_amdgcn_cvt_pk_f32_fp8(v1.y, false);
        floatx2 vh = __builtin_amdgcn_cvt_pk_f32_fp8(v1.y, true);

        l += w0 + w1;
        acc[0] = fmaf(w0, va.x, fmaf(w1, ve.x, acc[0]));
        acc[1] = fmaf(w0, va.y, fmaf(w1, ve.y, acc[1]));
        acc[2] = fmaf(w0, vb.x, fmaf(w1, vf.x, acc[2]));
        acc[3] = fmaf(w0, vb.y, fmaf(w1, vf.y, acc[3]));
        acc[4] = fmaf(w0, vc.x, fmaf(w1, vg.x, acc[4]));
        acc[5] = fmaf(w0, vc.y, fmaf(w1, vg.y, acc[5]));
        acc[6] = fmaf(w0, vd.x, fmaf(w1, vh.x, acc[6]));
        acc[7] = fmaf(w0, vd.y, fmaf(w1, vh.y, acc[7]));
    }

    #pragma unroll
    for (int i = 0; i < 8; ++i) {
        acc[i] += __shfl_xor(acc[i], 16, 64);
        acc[i] += __shfl_xor(acc[i], 32, 64);
    }
    l += __shfl_xor(l, 16, 64);
    l += __shfl_xor(l, 32, 64);

    const float inv = 1.0f / ((l == 0.f) ? 1.f : l);
    const int fo = f0 + g * 2;                          // lane stores 2 feats
    const uint_t su = *(const uint_t*)(sp + ((size_t)dst << 7) + fo);
    float ox = acc[g * 2]     * inv + bf2f_lo(su);
    float oy = acc[g * 2 + 1] * inv + bf2f_hi(su);
    if (relu) { ox = fmaxf(ox, 0.f); oy = fmaxf(oy, 0.f); }
    if (bf16out) {
        ushort_t p2[2] = {f2bf(ox), f2bf(oy)};
        *(uint_t*)(out_bf + ((size_t)dst << 7) + fo) = *(uint_t*)p2;
    } else {
        *(float2*)(out_f + ((size_t)dst << 7) + fo) = make_float2(ox, oy);
    }
}

// ---------------- launch ----------------
extern "C" void kernel_launch(void* const* d_in, const int* in_sizes, int n_in,
                              void* d_out, int out_size, void* d_ws, size_t ws_size,
                              hipStream_t stream) {
    const float* x  = (const float*)d_in[0];
    const int*   ei = (const int*)d_in[1];   // [2,E]: row0=src, row1=dst
    const float* Wq1 = (const float*)d_in[2],  *bq1 = (const float*)d_in[3];
    const float* Wk1 = (const float*)d_in[4],  *bk1 = (const float*)d_in[5];
    const float* Wv1 = (const float*)d_in[6],  *bv1 = (const float*)d_in[7];
    const float* Ws1 = (const float*)d_in[8],  *bs1 = (const float*)d_in[9];
    const float* Wq2 = (const float*)d_in[10], *bq2 = (const float*)d_in[11];
    const float* Wk2 = (const float*)d_in[12], *bk2 = (const float*)d_in[13];
    const float* Wv2 = (const float*)d_in[14], *bv2 = (const float*)d_in[15];
    const float* Ws2 = (const float*)d_in[16], *bs2 = (const float*)d_in[17];

    char* ws = (char*)d_ws;
    int* deg     = (int*)(ws + WS_DEG);
    int* cursor  = (int*)(ws + WS_CURSOR);
    int* bcur    = (int*)(ws + WS_BCUR);
    int* off     = (int*)(ws + WS_OFF);
    int* aux     = (int*)(ws + WS_AUX);
    ushort_t* esrc = (ushort_t*)(ws + WS_ESRC);
    ushort_t* wt = (ushort_t*)(ws + WS_WT);
    uint_t* staging = (uint_t*)(ws + WS_STAGE);
    ushort_t* hb = (ushort_t*)(ws + WS_HB);
    ushort_t* q  = (ushort_t*)(ws + WS_Q);
    uchar_t*  k8 = (uchar_t*)(ws + WS_K);
    uchar_t*  v8 = (uchar_t*)(ws + WS_V);
    ushort_t* s  = (ushort_t*)(ws + WS_S);
    float* out = (float*)d_out;

    const int gblocks = (N_NODES + 63) / 64;          // 782
    const int attn_blocks = (N_NODES + 3) / 4;        // 12500
    const int sblocks = (N_NODES + 255) / 256;        // 196
    const int binblocks = (N_EDGES + 2047) / 2048;    // 391

    // zero deg + cursor + bucket cursors
    hipMemsetAsync(ws + WS_DEG, 0, 400256, stream);

    // fused: weight transpose (blocks 0..63) + edge binning + deg hist (64..)
    prep_k<<<64 + binblocks, 256, 0, stream>>>(Wq1, Wk1, Wv1, Ws1, Wq2, Wk2, Wv2, Ws2,
                                               wt, ei, deg, bcur, staging);

    // parallel scan -> off[]
    scan1_k<<<sblocks, 256, 0, stream>>>(deg, off, aux, N_NODES);
    scan2_k<<<1, 256, 0, stream>>>(aux, off, sblocks, N_NODES, N_EDGES);
    scan3_k<<<sblocks, 256, 0, stream>>>(off, aux, N_NODES);

    // bucketed CSR scatter (writes land in ~32 KB L2-hot windows)
    binscat_k<<<dim3(49, 8), 256, 0, stream>>>(staging, bcur, off, cursor, esrc);

    // layer 1 (fp32 x, converted during staging)
    gemm_mfma_k<<<gblocks, 256, 0, stream>>>(x, 1, wt, bq1, bk1, bv1, bs1,
                                             q, k8, v8, s, N_NODES);
    attn_k<<<attn_blocks, 256, 0, stream>>>(q, k8, v8, s, off, esrc, hb, nullptr,
                                            1, 1, N_NODES);

    // layer 2 (bf16 h)
    gemm_mfma_k<<<gblocks, 256, 0, stream>>>(hb, 0, wt + 4 * FD * FD, bq2, bk2, bv2, bs2,
                                             q, k8, v8, s, N_NODES);
    attn_k<<<attn_blocks, 256, 0, stream>>>(q, k8, v8, s, off, esrc, nullptr, out,
                                            0, 0, N_NODES);
}